// Round 10
// baseline (78.524 us; speedup 1.0000x reference)
//
#include <hip/hip_runtime.h>
#include <math.h>

namespace {
constexpr int kB = 32;
constexpr int kN = 100000;
constexpr int kL = 12;
constexpr int kS = 256;
constexpr int kBG = 16;                     // poses per block in deform kernel
constexpr int kWOwn = 62;                   // atoms OWNED per wave (2 shuffle-halo lanes)
constexpr int kTile = 4 * kWOwn;            // 248 atoms owned per 256-thread block
constexpr int kNB = (kN + kTile - 1) / kTile;  // 404 atom-blocks
constexpr int kCap = 16384;                 // per-(pose,band) bucket capacity
constexpr int kKx = 130;                    // stored kx columns (129 used + pad)

constexpr float kGauss = (float)(2.0 * M_PI * M_PI);                         // 2(pi*sigma)^2, sigma=1
constexpr float kA1 = (float)(M_PI * 0.0197);                                // pi*lambda
constexpr float kA2 = (float)(0.5 * M_PI * 2.7e7 * 0.0197 * 0.0197 * 0.0197);// 0.5*pi*Cs*lambda^3
constexpr float kW1 = 0.99498743710661995f;                                  // sqrt(1-Q0^2)
constexpr float kQ0 = 0.1f;
}

// ---------------------------------------------------------------------------
// Zero the 256-int gcount array (kernel node; blit memset measured unreliable).
// ---------------------------------------------------------------------------
__global__ __launch_bounds__(256) void k_zero(int* __restrict__ gcount) {
  gcount[threadIdx.x] = 0;
}

// ---------------------------------------------------------------------------
// 256-point Stockham radix-2 FFT in LDS with a shared twiddle table.
// 128 lanes per FFT, 8 stages, auto-sorting. Result ends in buffer `a`.
// tw[k] = (cos, sin)(pi*k/128); SIGN=-1 forward, +1 inverse.
// Contains __syncthreads(): all 256 threads of the block must call uniformly.
// ---------------------------------------------------------------------------
template <int SIGN>
__device__ __forceinline__ float2* fft256t(float2* a, float2* b, int lane,
                                           const float2* tw) {
#pragma unroll
  for (int m = 1; m <= 128; m <<= 1) {
    float2 c0 = a[lane];
    float2 c1 = a[lane + 128];
    int jm = lane & ~(m - 1);
    float2 w = tw[jm];
    float c = w.x;
    float s = (SIGN < 0) ? -w.y : w.y;
    float ex = c0.x + c1.x, ey = c0.y + c1.y;
    float dx = c0.x - c1.x, dy = c0.y - c1.y;
    b[lane + jm]     = make_float2(ex, ey);
    b[lane + jm + m] = make_float2(c * dx - s * dy, c * dy + s * dx);
    __syncthreads();
    float2* tp = a; a = b; b = tp;
  }
  return a;  // 8 swaps -> result back in original `a` buffer
}

__device__ __forceinline__ void build_tw(float2* tw, int t) {
  if (t < 128) {
    float s, c;
    sincosf((float)M_PI / 128.0f * (float)t, &s, &c);
    tw[t] = make_float2(c, s);
  }
}

// ---------------------------------------------------------------------------
// Phase A: deformation -> bond, angle, projected (x,y) packed u16.8 into
// per-(pose, 32-row band) compact bucket lists.
// Wave w owns atoms [blk*248 + w*62, +62); all 64 lanes compute (2 halo
// lanes); neighbors via __shfl_down. Per-pose rank via 3-ballot band match
// (one LDS atomic per wave-band, not per lane). 16 poses/block, gd.y=2.
// ---------------------------------------------------------------------------
__global__ __launch_bounds__(256) void k_deform(
    const float* __restrict__ c_nma, const float* __restrict__ delta_euler,
    const float* __restrict__ delta_shifts, const float* __restrict__ coords,
    const float* __restrict__ basis_x, const float* __restrict__ basis_y,
    const float* __restrict__ basis_z, const float* __restrict__ euler_base,
    const float* __restrict__ shifts_base,
    unsigned* __restrict__ xy_bkt, int* __restrict__ gcount,
    float* __restrict__ bond, float* __restrict__ angle) {
  __shared__ float cn_s[kBG][kL];
  __shared__ float rsh_s[kBG][8];
  __shared__ int bcnt[kBG][8];
  __shared__ int bbase[kBG][8];

  const int t = threadIdx.x;
  const int wave = t >> 6, lane = t & 63;
  const int bg = blockIdx.y * kBG;
  const int n = blockIdx.x * kTile + wave * kWOwn + lane;
  const bool owner = (lane < kWOwn) && (n < kN);
  const int nc = min(n, kN - 1);

  if (t < kBG * kL) cn_s[t / kL][t % kL] = c_nma[(bg + t / kL) * kL + (t % kL)];
  if (t < kBG) {
    int b = bg + t;
    float rot  = euler_base[b * 3 + 0] + delta_euler[b * 3 + 0];
    float tilt = euler_base[b * 3 + 1] + delta_euler[b * 3 + 1];
    float psi  = euler_base[b * 3 + 2] + delta_euler[b * 3 + 2];
    float ca = cosf(rot), sa = sinf(rot);
    float cb = cosf(tilt), sb = sinf(tilt);
    float cg = cosf(psi), sg = sinf(psi);
    rsh_s[t][0] = cg * cb * ca - sg * sa;
    rsh_s[t][1] = cg * cb * sa + sg * ca;
    rsh_s[t][2] = -cg * sb;
    rsh_s[t][3] = -sg * cb * ca - cg * sa;
    rsh_s[t][4] = -sg * cb * sa + cg * ca;
    rsh_s[t][5] = sg * sb;
    rsh_s[t][6] = shifts_base[b * 2 + 0] + delta_shifts[b * 2 + 0] + 128.0f;
    rsh_s[t][7] = shifts_base[b * 2 + 1] + delta_shifts[b * 2 + 1] + 128.0f;
  }
  if (t < kBG * 8) bcnt[t >> 3][t & 7] = 0;

  const float cx = coords[nc * 3 + 0];
  const float cy = coords[nc * 3 + 1];
  const float cz = coords[nc * 3 + 2];
  float bx[kL], by[kL], bz[kL];
  {
    const float4* px4 = reinterpret_cast<const float4*>(basis_x + (size_t)nc * kL);
    const float4* py4 = reinterpret_cast<const float4*>(basis_y + (size_t)nc * kL);
    const float4* pz4 = reinterpret_cast<const float4*>(basis_z + (size_t)nc * kL);
#pragma unroll
    for (int q = 0; q < 3; ++q) {
      float4 vx = px4[q], vy = py4[q], vz = pz4[q];
      bx[q * 4 + 0] = vx.x; bx[q * 4 + 1] = vx.y; bx[q * 4 + 2] = vx.z; bx[q * 4 + 3] = vx.w;
      by[q * 4 + 0] = vy.x; by[q * 4 + 1] = vy.y; by[q * 4 + 2] = vy.z; by[q * 4 + 3] = vy.w;
      bz[q * 4 + 0] = vz.x; bz[q * 4 + 1] = vz.y; bz[q * 4 + 2] = vz.z; bz[q * 4 + 3] = vz.w;
    }
  }
  const unsigned long long act = __ballot(owner);
  __syncthreads();

  unsigned ureg[kBG];   // packed (y<<16)|x per pose
  unsigned meta[kBG];   // (rank<<3)|band per pose

#pragma unroll
  for (int bi = 0; bi < kBG; ++bi) {
    const int b = bg + bi;
    float px = cx, py = cy, pz = cz;
#pragma unroll
    for (int l = 0; l < kL; ++l) {
      float cc = cn_s[bi][l];
      px = fmaf(cc, bx[l], px);
      py = fmaf(cc, by[l], py);
      pz = fmaf(cc, bz[l], pz);
    }
    // neighbor deltas via wave shuffles (computed by all 64 lanes)
    float p1x = __shfl_down(px, 1), p1y = __shfl_down(py, 1), p1z = __shfl_down(pz, 1);
    float dx = p1x - px, dy = p1y - py, dz = p1z - pz;
    float dd = fmaf(dx, dx, fmaf(dy, dy, dz * dz));
    float d1x = __shfl_down(dx, 1), d1y = __shfl_down(dy, 1), d1z = __shfl_down(dz, 1);

    // projection; quantize to u16.8 fixed point (floor), pack (y<<16)|x
    float xr = fmaf(rsh_s[bi][0], px, fmaf(rsh_s[bi][1], py, fmaf(rsh_s[bi][2], pz, rsh_s[bi][6])));
    float yr = fmaf(rsh_s[bi][3], px, fmaf(rsh_s[bi][4], py, fmaf(rsh_s[bi][5], pz, rsh_s[bi][7])));
    xr = fminf(fmaxf(xr, 0.0f), 254.999f);
    yr = fminf(fmaxf(yr, 0.0f), 254.999f);
    unsigned xf = (unsigned)(xr * 256.0f);   // <= 65279 -> x0 <= 254
    unsigned yf = (unsigned)(yr * 256.0f);
    unsigned band = yf >> 13;                // row>>5, 0..7

    // wave-level rank: match lanes with equal band via 3 ballots
    unsigned long long m = act;
#pragma unroll
    for (int bit = 0; bit < 3; ++bit) {
      unsigned long long bs = __ballot(((band >> bit) & 1u) != 0u);
      m &= ((band >> bit) & 1u) ? bs : ~bs;
    }
    int rank_in_wave = __popcll(m & ((1ull << lane) - 1ull));
    int leader = (int)(__ffsll((long long)m) - 1);
    int wbase = 0;
    if (lane == leader && m) wbase = atomicAdd(&bcnt[bi][band], (int)__popcll(m));
    wbase = __shfl(wbase, leader < 0 ? 0 : leader);
    ureg[bi] = (yf << 16) | xf;
    meta[bi] = ((unsigned)(wbase + rank_in_wave) << 3) | band;

    if (owner) {
      // bond length at n (atoms n, n+1)
      if (n < kN - 1) {
        __builtin_nontemporal_store(sqrtf(dd + 1e-12f),
                                    &bond[(size_t)b * (kN - 1) + n]);
      }
      // angle at interior atom n+1 (atoms n, n+1, n+2); fast acos
      if (n < kN - 2) {
        float vv = fmaf(d1x, d1x, fmaf(d1y, d1y, d1z * d1z));
        float uv = -fmaf(dx, d1x, fmaf(dy, d1y, dz * d1z));
        float cosang = uv * rsqrtf(dd * vv);
        cosang = fminf(fmaxf(cosang, -0.9999f), 0.9999f);
        float ax = fabsf(cosang);
        float rt = sqrtf(1.0f - ax);
        float pp = fmaf(fmaf(fmaf(-0.0187293f, ax, 0.0742610f), ax, -0.2121144f),
                        ax, 1.5707288f);
        float res = rt * pp;
        __builtin_nontemporal_store((cosang >= 0.f) ? res : (float)M_PI - res,
                                    &angle[(size_t)b * (kN - 2) + n]);
      }
    }
  }
  __syncthreads();
  if (t < kBG * 8) {
    int po = t >> 3, bandx = t & 7;
    int c = bcnt[po][bandx];
    bbase[po][bandx] = c ? atomicAdd(&gcount[(bg + po) * 8 + bandx], c) : 0;
  }
  __syncthreads();
#pragma unroll
  for (int bi = 0; bi < kBG; ++bi) {
    if (owner) {
      unsigned band = meta[bi] & 7;
      int pos = bbase[bi][band] + (int)(meta[bi] >> 3);
      if (pos < kCap) xy_bkt[((size_t)(bg + bi) * 8 + band) * kCap + pos] = ureg[bi];
    }
  }
}

// ---------------------------------------------------------------------------
// Phase B: bilinear splat from per-(pose,band) compact lists into a 33x256
// INTEGER (u18.14) LDS tile via native ds_add_u32. ALL outputs are plain
// stores: rows 0..31 -> img; r=32 overflow -> bnd[b][band][256] (added back
// at FFT-load time). img needs NO zero-init. grid: 32*8, 1024 threads.
// ---------------------------------------------------------------------------
__global__ __launch_bounds__(1024) void k_splat(const unsigned* __restrict__ xy_bkt,
                                                const int* __restrict__ gcount,
                                                float* __restrict__ img,
                                                float* __restrict__ bnd) {
  __shared__ unsigned tile[33 * 256];
  const int t = threadIdx.x;
  const int b = blockIdx.x >> 3;
  const int band = blockIdx.x & 7;
  const int r0 = band * 32;
  for (int i = t; i < 33 * 256; i += 1024) tile[i] = 0u;
  __syncthreads();

  const int c = min(gcount[b * 8 + band], kCap);
  const unsigned* seg = xy_bkt + ((size_t)b * 8 + band) * kCap;

  auto splat1 = [&](unsigned u) {
    int yf = (int)(u >> 16);
    int xf = (int)(u & 0xFFFFu);
    int ry = (yf >> 8) - r0;                 // guaranteed 0..31 by bucketing
    int x0 = xf >> 8;
    int fx = xf & 255, fy = yf & 255;        // u0.8 fractions
    int gx = 256 - fx, gy = 256 - fy;
    int base = ry * 256 + x0;
    // w * 2^14 = (w8a * w8b + 2) >> 2  (round-to-nearest-ish)
    atomicAdd(&tile[base],       (unsigned)((gx * gy + 2) >> 2));
    atomicAdd(&tile[base + 1],   (unsigned)((fx * gy + 2) >> 2));
    atomicAdd(&tile[base + 256], (unsigned)((gx * fy + 2) >> 2));
    atomicAdd(&tile[base + 257], (unsigned)((fx * fy + 2) >> 2));
  };

  const int c4 = c & ~3;
  const uint4* seg4 = reinterpret_cast<const uint4*>(seg);
  for (int i4 = t; i4 * 4 < c4; i4 += 1024) {
    uint4 q = seg4[i4];
    splat1(q.x); splat1(q.y); splat1(q.z); splat1(q.w);
  }
  for (int i = c4 + t; i < c; i += 1024) splat1(seg[i]);
  __syncthreads();

  const int col = t & 255;
  for (int r = (t >> 8); r < 33; r += 4) {
    float v = (float)tile[r * 256 + col] * (1.0f / 16384.0f);
    if (r < 32)          img[((size_t)b * kS + r0 + r) * kS + col] = v;
    else if (band < 7)   bnd[((size_t)b * 7 + band) * kS + col] = v;
  }
}

// ---------------------------------------------------------------------------
// FFT passes with real-FFT packing (2 real rows per complex FFT) and
// Hermitian-reduced spectrum: only kx = 0..128 stored, TRANSPOSED:
// FcT[b][kx][y], kx-stride kKx=130.
// ---------------------------------------------------------------------------
__global__ __launch_bounds__(256) void k_fft_rows_fwd(const float* __restrict__ img,
                                                      const float* __restrict__ bnd,
                                                      float2* __restrict__ FcT) {
  __shared__ float2 smA[2][256];
  __shared__ float2 smB[2][256];
  __shared__ float2 tw[128];
  const int t = threadIdx.x, half = t >> 7, lane = t & 127;
  build_tw(tw, t);
  const int b = blockIdx.x >> 6;
  const int y0 = (blockIdx.x & 63) * 4;

  // pack rows (y0+2h, y0+2h+1) as re+i*im; add band-overflow to rows %32==0
  const float* rA = img + ((size_t)b * kS + y0 + 2 * half) * kS;
  const float* rB = rA + kS;
  float eA0 = 0.f, eA1 = 0.f;
  if (half == 0 && y0 != 0 && (y0 & 31) == 0) {
    const float* bp = bnd + ((size_t)b * 7 + (y0 >> 5) - 1) * kS;
    eA0 = bp[lane]; eA1 = bp[lane + 128];
  }
  float2* a = smA[half];
  a[lane]       = make_float2(rA[lane] + eA0,       rB[lane]);
  a[lane + 128] = make_float2(rA[lane + 128] + eA1, rB[lane + 128]);
  __syncthreads();
  fft256t<-1>(a, smB[half], lane, tw);   // result in smA[half]

  // unpack 4 row-spectra at k=t (t<=128) and transpose-write 32B chunks
  if (t <= 128) {
    int tm = (256 - t) & 255;
    float2 Zk0 = smA[0][t], Zm0 = smA[0][tm];
    float2 Zk1 = smA[1][t], Zm1 = smA[1][tm];
    float4 o0 = make_float4(0.5f * (Zk0.x + Zm0.x), 0.5f * (Zk0.y - Zm0.y),
                            0.5f * (Zk0.y + Zm0.y), 0.5f * (Zm0.x - Zk0.x));
    float4 o1 = make_float4(0.5f * (Zk1.x + Zm1.x), 0.5f * (Zk1.y - Zm1.y),
                            0.5f * (Zk1.y + Zm1.y), 0.5f * (Zm1.x - Zk1.x));
    float4* o = reinterpret_cast<float4*>(FcT + ((size_t)b * kKx + t) * kS + y0);
    o[0] = o0;
    o[1] = o1;
  }
}

__global__ __launch_bounds__(256) void k_fft_cols(float2* __restrict__ FcT,
                                                  const float* __restrict__ defocus) {
  __shared__ float2 sm[4][256];
  __shared__ float2 tw[128];
  const int t = threadIdx.x, half = t >> 7, lane = t & 127;
  build_tw(tw, t);
  const int b = blockIdx.x / 65, kxp = blockIdx.x % 65;
  const int kx = kxp * 2 + half;          // 0..129; 129 is duplicate work
  const int kxr = min(kx, 128);
  float2* col = FcT + ((size_t)b * kKx + kxr) * kS;   // contiguous column
  float2* a = sm[half * 2];
  float2* bb = sm[half * 2 + 1];
  __syncthreads();
  a[lane]       = col[lane];
  a[lane + 128] = col[lane + 128];
  float2* r1 = fft256t<-1>(a, bb, lane, tw);

  // apply real filter H(ky,kx) = G * CTF (defocus-dependent per pose)
  const float D = defocus[b];
  const float fxv = (float)kxr * (1.0f / 256.0f);     // rfftfreq: 0..0.5
  const float fx2 = fxv * fxv;
#pragma unroll
  for (int h = 0; h < 2; ++h) {
    int ky = lane + h * 128;
    float fyv = (float)(ky < 128 ? ky : ky - 256) * (1.0f / 256.0f);
    float s2 = fyv * fyv + fx2;
    float G = __expf(-kGauss * s2);
    float chi = kA1 * D * s2 - kA2 * s2 * s2;
    float sn, cn;
    sincosf(chi, &sn, &cn);
    float H = G * (-(kW1 * sn + kQ0 * cn));
    r1[ky].x *= H;
    r1[ky].y *= H;
  }
  float2* r2 = (r1 == a) ? bb : a;
  float2* res = fft256t<1>(r1, r2, lane, tw);
  if (kx <= 128) {
    col[lane]       = res[lane];
    col[lane + 128] = res[lane + 128];
  }
}

__global__ __launch_bounds__(256) void k_fft_rows_inv(const float2* __restrict__ FcT,
                                                      float* __restrict__ out) {
  __shared__ float2 smA[2][256];
  __shared__ float2 smB[2][256];
  __shared__ float2 smT[130 * 5];          // [k][r], stride 5 to spread banks
  __shared__ float2 tw[128];
  const int t = threadIdx.x, half = t >> 7, lane = t & 127;
  build_tw(tw, t);
  const int b = blockIdx.x >> 6;
  const int y0 = (blockIdx.x & 63) * 4;

  // stage T(k, y0..y0+3), k = 0..128 (transpose read, 32B chunks)
  if (t < 129) {
    const float4* ip =
        reinterpret_cast<const float4*>(FcT + ((size_t)b * kKx + t) * kS + y0);
    float4 w0 = ip[0], w1 = ip[1];
    smT[t * 5 + 0] = make_float2(w0.x, w0.y);
    smT[t * 5 + 1] = make_float2(w0.z, w0.w);
    smT[t * 5 + 2] = make_float2(w1.x, w1.y);
    smT[t * 5 + 3] = make_float2(w1.z, w1.w);
  }
  __syncthreads();

  // build Z(k) = T1(k) + i*T2(k) with Hermitian extension for k>128
  float2* a = smA[half];
  {
    float2 T1 = smT[lane * 5 + 2 * half], T2 = smT[lane * 5 + 2 * half + 1];
    a[lane] = make_float2(T1.x - T2.y, T1.y + T2.x);
    int km = (lane == 0) ? 128 : (128 - lane);
    float2 T1m = smT[km * 5 + 2 * half], T2m = smT[km * 5 + 2 * half + 1];
    a[lane + 128] = (lane == 0)
        ? make_float2(T1m.x - T2m.y, T1m.y + T2m.x)
        : make_float2(T1m.x + T2m.y, -T1m.y + T2m.x);
  }
  __syncthreads();
  float2* res = fft256t<1>(a, smB[half], lane, tw);  // rows y0+2h, y0+2h+1

  float* o0 = out + ((size_t)b * kS + y0 + 2 * half) * kS;
  float* o1 = o0 + kS;
  o0[lane]       = res[lane].x * (1.0f / 65536.0f);
  o0[lane + 128] = res[lane + 128].x * (1.0f / 65536.0f);
  o1[lane]       = res[lane].y * (1.0f / 65536.0f);
  o1[lane + 128] = res[lane + 128].y * (1.0f / 65536.0f);
}

// ---------------------------------------------------------------------------
extern "C" void kernel_launch(void* const* d_in, const int* in_sizes, int n_in,
                              void* d_out, int out_size, void* d_ws, size_t ws_size,
                              hipStream_t stream) {
  const float* c_nma        = (const float*)d_in[0];
  const float* delta_euler  = (const float*)d_in[1];
  const float* delta_shifts = (const float*)d_in[2];
  const float* coords       = (const float*)d_in[3];
  const float* basis_x      = (const float*)d_in[4];
  const float* basis_y      = (const float*)d_in[5];
  const float* basis_z      = (const float*)d_in[6];
  const float* euler_base   = (const float*)d_in[7];
  const float* shifts_base  = (const float*)d_in[8];
  const float* defocus      = (const float*)d_in[9];

  float* out = (float*)d_out;
  float* decoded = out;                                   // B*S*S
  float* bond    = out + (size_t)kB * kS * kS;            // B*(N-1)
  float* angle   = bond + (size_t)kB * (kN - 1);          // B*(N-2)

  char* ws = (char*)d_ws;
  const size_t imgBytes = (size_t)kB * kS * kS * sizeof(float);        // 8 MB
  float*    img    = (float*)ws;                           // [0, 8MB)
  unsigned* xy_bkt = (unsigned*)(ws + imgBytes);           // [8MB, 24MB) dead after k_splat
  float2*   FcT    = (float2*)(ws + imgBytes);             // [8MB, 16.5MB) aliases xy_bkt (after splat)
  int*      gcount = (int*)(ws + imgBytes + (size_t)17 * 1024 * 1024);  // [25MB, +1KB)
  float*    bnd    = (float*)(ws + imgBytes + (size_t)18 * 1024 * 1024);// [26MB, +229KB)

  k_zero<<<1, 256, 0, stream>>>(gcount);

  dim3 gd(kNB, kB / kBG);
  k_deform<<<gd, 256, 0, stream>>>(c_nma, delta_euler, delta_shifts, coords,
                                   basis_x, basis_y, basis_z, euler_base,
                                   shifts_base, xy_bkt, gcount, bond, angle);
  k_splat<<<kB * 8, 1024, 0, stream>>>(xy_bkt, gcount, img, bnd);
  k_fft_rows_fwd<<<kB * 64, 256, 0, stream>>>(img, bnd, FcT);
  k_fft_cols<<<kB * 65, 256, 0, stream>>>(FcT, defocus);
  k_fft_rows_inv<<<kB * 64, 256, 0, stream>>>(FcT, decoded);
}

// Round 11
// 72.308 us; speedup vs baseline: 1.0860x; 1.0860x over previous
//
#include <hip/hip_runtime.h>
#include <math.h>

namespace {
constexpr int kB = 32;
constexpr int kN = 100000;
constexpr int kL = 12;
constexpr int kS = 256;
constexpr int kBG = 8;                      // poses per block in deform kernel
constexpr int kWOwn = 62;                   // atoms OWNED per wave (2 shuffle-halo lanes)
constexpr int kTile = 4 * kWOwn;            // 248 atoms owned per 256-thread block
constexpr int kNB = (kN + kTile - 1) / kTile;  // 404 atom-blocks
constexpr int kCap = 16384;                 // per-(pose,band) bucket capacity
constexpr int kKx = 130;                    // stored kx columns (129 used + pad)
constexpr int kGPad = 16;                   // gcount stride in ints (64B = 1 line/counter)

constexpr float kGauss = (float)(2.0 * M_PI * M_PI);                         // 2(pi*sigma)^2, sigma=1
constexpr float kA1 = (float)(M_PI * 0.0197);                                // pi*lambda
constexpr float kA2 = (float)(0.5 * M_PI * 2.7e7 * 0.0197 * 0.0197 * 0.0197);// 0.5*pi*Cs*lambda^3
constexpr float kW1 = 0.99498743710661995f;                                  // sqrt(1-Q0^2)
constexpr float kQ0 = 0.1f;
}

// ---------------------------------------------------------------------------
// Zero the padded gcount array (256 counters * 16-int stride = 16 KB).
// ---------------------------------------------------------------------------
__global__ __launch_bounds__(256) void k_zero(int* __restrict__ gcount) {
  const int t = threadIdx.x;
#pragma unroll
  for (int i = 0; i < kB * 8 * kGPad / 256; ++i) gcount[i * 256 + t] = 0;
}

// ---------------------------------------------------------------------------
// 256-point Stockham radix-2 FFT in LDS with a shared twiddle table.
// 128 lanes per FFT, 8 stages, auto-sorting. Result ends in buffer `a`.
// tw[k] = (cos, sin)(pi*k/128); SIGN=-1 forward, +1 inverse.
// Contains __syncthreads(): all 256 threads of the block must call uniformly.
// ---------------------------------------------------------------------------
template <int SIGN>
__device__ __forceinline__ float2* fft256t(float2* a, float2* b, int lane,
                                           const float2* tw) {
#pragma unroll
  for (int m = 1; m <= 128; m <<= 1) {
    float2 c0 = a[lane];
    float2 c1 = a[lane + 128];
    int jm = lane & ~(m - 1);
    float2 w = tw[jm];
    float c = w.x;
    float s = (SIGN < 0) ? -w.y : w.y;
    float ex = c0.x + c1.x, ey = c0.y + c1.y;
    float dx = c0.x - c1.x, dy = c0.y - c1.y;
    b[lane + jm]     = make_float2(ex, ey);
    b[lane + jm + m] = make_float2(c * dx - s * dy, c * dy + s * dx);
    __syncthreads();
    float2* tp = a; a = b; b = tp;
  }
  return a;  // 8 swaps -> result back in original `a` buffer
}

__device__ __forceinline__ void build_tw(float2* tw, int t) {
  if (t < 128) {
    float s, c;
    sincosf((float)M_PI / 128.0f * (float)t, &s, &c);
    tw[t] = make_float2(c, s);
  }
}

// ---------------------------------------------------------------------------
// Phase A: deformation -> bond, angle, projected (x,y) packed u16.8 into
// per-(pose, 32-row band) compact bucket lists.
// Wave w owns atoms [blk*248 + w*62, +62); all 64 lanes compute (2 halo
// lanes); neighbors via __shfl_down, no barriers in the pose loop.
// Batched reservation: ONE padded global atomic per (pose,band) per block.
// ---------------------------------------------------------------------------
__global__ __launch_bounds__(256) void k_deform(
    const float* __restrict__ c_nma, const float* __restrict__ delta_euler,
    const float* __restrict__ delta_shifts, const float* __restrict__ coords,
    const float* __restrict__ basis_x, const float* __restrict__ basis_y,
    const float* __restrict__ basis_z, const float* __restrict__ euler_base,
    const float* __restrict__ shifts_base,
    unsigned* __restrict__ xy_bkt, int* __restrict__ gcount,
    float* __restrict__ bond, float* __restrict__ angle) {
  __shared__ float cn_s[kBG][kL];
  __shared__ float rsh_s[kBG][8];
  __shared__ int bcnt[kBG][8];
  __shared__ int bbase[kBG][8];

  const int t = threadIdx.x;
  const int wave = t >> 6, lane = t & 63;
  const int bg = blockIdx.y * kBG;
  const int n = blockIdx.x * kTile + wave * kWOwn + lane;
  const bool owner = (lane < kWOwn) && (n < kN);
  const int nc = min(n, kN - 1);

  if (t < kBG * kL) cn_s[t / kL][t % kL] = c_nma[(bg + t / kL) * kL + (t % kL)];
  if (t < kBG) {
    int b = bg + t;
    float rot  = euler_base[b * 3 + 0] + delta_euler[b * 3 + 0];
    float tilt = euler_base[b * 3 + 1] + delta_euler[b * 3 + 1];
    float psi  = euler_base[b * 3 + 2] + delta_euler[b * 3 + 2];
    float ca = cosf(rot), sa = sinf(rot);
    float cb = cosf(tilt), sb = sinf(tilt);
    float cg = cosf(psi), sg = sinf(psi);
    rsh_s[t][0] = cg * cb * ca - sg * sa;
    rsh_s[t][1] = cg * cb * sa + sg * ca;
    rsh_s[t][2] = -cg * sb;
    rsh_s[t][3] = -sg * cb * ca - cg * sa;
    rsh_s[t][4] = -sg * cb * sa + cg * ca;
    rsh_s[t][5] = sg * sb;
    rsh_s[t][6] = shifts_base[b * 2 + 0] + delta_shifts[b * 2 + 0] + 128.0f;
    rsh_s[t][7] = shifts_base[b * 2 + 1] + delta_shifts[b * 2 + 1] + 128.0f;
  }
  if (t < kBG * 8) bcnt[t >> 3][t & 7] = 0;

  const float cx = coords[nc * 3 + 0];
  const float cy = coords[nc * 3 + 1];
  const float cz = coords[nc * 3 + 2];
  float bx[kL], by[kL], bz[kL];
  {
    const float4* px4 = reinterpret_cast<const float4*>(basis_x + (size_t)nc * kL);
    const float4* py4 = reinterpret_cast<const float4*>(basis_y + (size_t)nc * kL);
    const float4* pz4 = reinterpret_cast<const float4*>(basis_z + (size_t)nc * kL);
#pragma unroll
    for (int q = 0; q < 3; ++q) {
      float4 vx = px4[q], vy = py4[q], vz = pz4[q];
      bx[q * 4 + 0] = vx.x; bx[q * 4 + 1] = vx.y; bx[q * 4 + 2] = vx.z; bx[q * 4 + 3] = vx.w;
      by[q * 4 + 0] = vy.x; by[q * 4 + 1] = vy.y; by[q * 4 + 2] = vy.z; by[q * 4 + 3] = vy.w;
      bz[q * 4 + 0] = vz.x; bz[q * 4 + 1] = vz.y; bz[q * 4 + 2] = vz.z; bz[q * 4 + 3] = vz.w;
    }
  }
  __syncthreads();

  unsigned ureg[kBG];   // packed (y<<16)|x per pose
  unsigned meta[kBG];   // (rank<<3)|band per pose

#pragma unroll
  for (int bi = 0; bi < kBG; ++bi) {
    const int b = bg + bi;
    float px = cx, py = cy, pz = cz;
#pragma unroll
    for (int l = 0; l < kL; ++l) {
      float cc = cn_s[bi][l];
      px = fmaf(cc, bx[l], px);
      py = fmaf(cc, by[l], py);
      pz = fmaf(cc, bz[l], pz);
    }
    // neighbor deltas via wave shuffles (computed by all 64 lanes)
    float p1x = __shfl_down(px, 1), p1y = __shfl_down(py, 1), p1z = __shfl_down(pz, 1);
    float dx = p1x - px, dy = p1y - py, dz = p1z - pz;
    float dd = fmaf(dx, dx, fmaf(dy, dy, dz * dz));
    float d1x = __shfl_down(dx, 1), d1y = __shfl_down(dy, 1), d1z = __shfl_down(dz, 1);

    ureg[bi] = 0; meta[bi] = 0;
    if (owner) {
      // projection; quantize to u16.8 fixed point (floor), pack (y<<16)|x
      float xr = fmaf(rsh_s[bi][0], px, fmaf(rsh_s[bi][1], py, fmaf(rsh_s[bi][2], pz, rsh_s[bi][6])));
      float yr = fmaf(rsh_s[bi][3], px, fmaf(rsh_s[bi][4], py, fmaf(rsh_s[bi][5], pz, rsh_s[bi][7])));
      xr = fminf(fmaxf(xr, 0.0f), 254.999f);
      yr = fminf(fmaxf(yr, 0.0f), 254.999f);
      unsigned xf = (unsigned)(xr * 256.0f);   // <= 65279 -> x0 <= 254
      unsigned yf = (unsigned)(yr * 256.0f);
      unsigned band = yf >> 13;                // row>>5, 0..7
      int rank = atomicAdd(&bcnt[bi][band], 1);
      ureg[bi] = (yf << 16) | xf;
      meta[bi] = ((unsigned)rank << 3) | band;
      // bond length at n (atoms n, n+1)
      if (n < kN - 1) {
        __builtin_nontemporal_store(sqrtf(dd + 1e-12f),
                                    &bond[(size_t)b * (kN - 1) + n]);
      }
      // angle at interior atom n+1 (u = -d, v = d1); fast acos
      if (n < kN - 2) {
        float vv = fmaf(d1x, d1x, fmaf(d1y, d1y, d1z * d1z));
        float uv = -fmaf(dx, d1x, fmaf(dy, d1y, dz * d1z));
        float cosang = uv * rsqrtf(dd * vv);
        cosang = fminf(fmaxf(cosang, -0.9999f), 0.9999f);
        float ax = fabsf(cosang);
        float rt = sqrtf(1.0f - ax);
        float pp = fmaf(fmaf(fmaf(-0.0187293f, ax, 0.0742610f), ax, -0.2121144f),
                        ax, 1.5707288f);
        float res = rt * pp;
        __builtin_nontemporal_store((cosang >= 0.f) ? res : (float)M_PI - res,
                                    &angle[(size_t)b * (kN - 2) + n]);
      }
    }
  }
  __syncthreads();
  if (t < kBG * 8) {
    int po = t >> 3, bandx = t & 7;
    int c = bcnt[po][bandx];
    bbase[po][bandx] =
        c ? atomicAdd(&gcount[((bg + po) * 8 + bandx) * kGPad], c) : 0;
  }
  __syncthreads();
#pragma unroll
  for (int bi = 0; bi < kBG; ++bi) {
    if (owner) {
      unsigned band = meta[bi] & 7;
      int pos = bbase[bi][band] + (int)(meta[bi] >> 3);
      if (pos < kCap) xy_bkt[((size_t)(bg + bi) * 8 + band) * kCap + pos] = ureg[bi];
    }
  }
}

// ---------------------------------------------------------------------------
// Phase B: bilinear splat from per-(pose,band) compact lists into a 33x256
// INTEGER (u18.14) LDS tile via native ds_add_u32. ALL outputs are plain
// stores: rows 0..31 -> img; r=32 overflow -> bnd[b][band][256] (added back
// at FFT-load time). img needs NO zero-init. grid: 32*8, 1024 threads.
// ---------------------------------------------------------------------------
__global__ __launch_bounds__(1024) void k_splat(const unsigned* __restrict__ xy_bkt,
                                                const int* __restrict__ gcount,
                                                float* __restrict__ img,
                                                float* __restrict__ bnd) {
  __shared__ unsigned tile[33 * 256];
  const int t = threadIdx.x;
  const int b = blockIdx.x >> 3;
  const int band = blockIdx.x & 7;
  const int r0 = band * 32;
  for (int i = t; i < 33 * 256; i += 1024) tile[i] = 0u;
  __syncthreads();

  const int c = min(gcount[(b * 8 + band) * kGPad], kCap);
  const unsigned* seg = xy_bkt + ((size_t)b * 8 + band) * kCap;

  auto splat1 = [&](unsigned u) {
    int yf = (int)(u >> 16);
    int xf = (int)(u & 0xFFFFu);
    int ry = (yf >> 8) - r0;                 // guaranteed 0..31 by bucketing
    int x0 = xf >> 8;
    int fx = xf & 255, fy = yf & 255;        // u0.8 fractions
    int gx = 256 - fx, gy = 256 - fy;
    int base = ry * 256 + x0;
    // w * 2^14 = (w8a * w8b + 2) >> 2  (round-to-nearest-ish)
    atomicAdd(&tile[base],       (unsigned)((gx * gy + 2) >> 2));
    atomicAdd(&tile[base + 1],   (unsigned)((fx * gy + 2) >> 2));
    atomicAdd(&tile[base + 256], (unsigned)((gx * fy + 2) >> 2));
    atomicAdd(&tile[base + 257], (unsigned)((fx * fy + 2) >> 2));
  };

  const int c4 = c & ~3;
  const uint4* seg4 = reinterpret_cast<const uint4*>(seg);
  for (int i4 = t; i4 * 4 < c4; i4 += 1024) {
    uint4 q = seg4[i4];
    splat1(q.x); splat1(q.y); splat1(q.z); splat1(q.w);
  }
  for (int i = c4 + t; i < c; i += 1024) splat1(seg[i]);
  __syncthreads();

  const int col = t & 255;
  for (int r = (t >> 8); r < 33; r += 4) {
    float v = (float)tile[r * 256 + col] * (1.0f / 16384.0f);
    if (r < 32)          img[((size_t)b * kS + r0 + r) * kS + col] = v;
    else if (band < 7)   bnd[((size_t)b * 7 + band) * kS + col] = v;
  }
}

// ---------------------------------------------------------------------------
// FFT passes with real-FFT packing (2 real rows per complex FFT) and
// Hermitian-reduced spectrum: only kx = 0..128 stored, TRANSPOSED:
// FcT[b][kx][y], kx-stride kKx=130.
// ---------------------------------------------------------------------------
__global__ __launch_bounds__(256) void k_fft_rows_fwd(const float* __restrict__ img,
                                                      const float* __restrict__ bnd,
                                                      float2* __restrict__ FcT) {
  __shared__ float2 smA[2][256];
  __shared__ float2 smB[2][256];
  __shared__ float2 tw[128];
  const int t = threadIdx.x, half = t >> 7, lane = t & 127;
  build_tw(tw, t);
  const int b = blockIdx.x >> 6;
  const int y0 = (blockIdx.x & 63) * 4;

  // pack rows (y0+2h, y0+2h+1) as re+i*im; add band-overflow to rows %32==0
  const float* rA = img + ((size_t)b * kS + y0 + 2 * half) * kS;
  const float* rB = rA + kS;
  float eA0 = 0.f, eA1 = 0.f;
  if (half == 0 && y0 != 0 && (y0 & 31) == 0) {
    const float* bp = bnd + ((size_t)b * 7 + (y0 >> 5) - 1) * kS;
    eA0 = bp[lane]; eA1 = bp[lane + 128];
  }
  float2* a = smA[half];
  a[lane]       = make_float2(rA[lane] + eA0,       rB[lane]);
  a[lane + 128] = make_float2(rA[lane + 128] + eA1, rB[lane + 128]);
  __syncthreads();
  fft256t<-1>(a, smB[half], lane, tw);   // result in smA[half]

  // unpack 4 row-spectra at k=t (t<=128) and transpose-write 32B chunks
  if (t <= 128) {
    int tm = (256 - t) & 255;
    float2 Zk0 = smA[0][t], Zm0 = smA[0][tm];
    float2 Zk1 = smA[1][t], Zm1 = smA[1][tm];
    float4 o0 = make_float4(0.5f * (Zk0.x + Zm0.x), 0.5f * (Zk0.y - Zm0.y),
                            0.5f * (Zk0.y + Zm0.y), 0.5f * (Zm0.x - Zk0.x));
    float4 o1 = make_float4(0.5f * (Zk1.x + Zm1.x), 0.5f * (Zk1.y - Zm1.y),
                            0.5f * (Zk1.y + Zm1.y), 0.5f * (Zm1.x - Zk1.x));
    float4* o = reinterpret_cast<float4*>(FcT + ((size_t)b * kKx + t) * kS + y0);
    o[0] = o0;
    o[1] = o1;
  }
}

__global__ __launch_bounds__(256) void k_fft_cols(float2* __restrict__ FcT,
                                                  const float* __restrict__ defocus) {
  __shared__ float2 sm[4][256];
  __shared__ float2 tw[128];
  const int t = threadIdx.x, half = t >> 7, lane = t & 127;
  build_tw(tw, t);
  const int b = blockIdx.x / 65, kxp = blockIdx.x % 65;
  const int kx = kxp * 2 + half;          // 0..129; 129 is duplicate work
  const int kxr = min(kx, 128);
  float2* col = FcT + ((size_t)b * kKx + kxr) * kS;   // contiguous column
  float2* a = sm[half * 2];
  float2* bb = sm[half * 2 + 1];
  __syncthreads();
  a[lane]       = col[lane];
  a[lane + 128] = col[lane + 128];
  float2* r1 = fft256t<-1>(a, bb, lane, tw);

  // apply real filter H(ky,kx) = G * CTF (defocus-dependent per pose)
  const float D = defocus[b];
  const float fxv = (float)kxr * (1.0f / 256.0f);     // rfftfreq: 0..0.5
  const float fx2 = fxv * fxv;
#pragma unroll
  for (int h = 0; h < 2; ++h) {
    int ky = lane + h * 128;
    float fyv = (float)(ky < 128 ? ky : ky - 256) * (1.0f / 256.0f);
    float s2 = fyv * fyv + fx2;
    float G = __expf(-kGauss * s2);
    float chi = kA1 * D * s2 - kA2 * s2 * s2;
    float sn, cn;
    sincosf(chi, &sn, &cn);
    float H = G * (-(kW1 * sn + kQ0 * cn));
    r1[ky].x *= H;
    r1[ky].y *= H;
  }
  float2* r2 = (r1 == a) ? bb : a;
  float2* res = fft256t<1>(r1, r2, lane, tw);
  if (kx <= 128) {
    col[lane]       = res[lane];
    col[lane + 128] = res[lane + 128];
  }
}

__global__ __launch_bounds__(256) void k_fft_rows_inv(const float2* __restrict__ FcT,
                                                      float* __restrict__ out) {
  __shared__ float2 smA[2][256];
  __shared__ float2 smB[2][256];
  __shared__ float2 smT[130 * 5];          // [k][r], stride 5 to spread banks
  __shared__ float2 tw[128];
  const int t = threadIdx.x, half = t >> 7, lane = t & 127;
  build_tw(tw, t);
  const int b = blockIdx.x >> 6;
  const int y0 = (blockIdx.x & 63) * 4;

  // stage T(k, y0..y0+3), k = 0..128 (transpose read, 32B chunks)
  if (t < 129) {
    const float4* ip =
        reinterpret_cast<const float4*>(FcT + ((size_t)b * kKx + t) * kS + y0);
    float4 w0 = ip[0], w1 = ip[1];
    smT[t * 5 + 0] = make_float2(w0.x, w0.y);
    smT[t * 5 + 1] = make_float2(w0.z, w0.w);
    smT[t * 5 + 2] = make_float2(w1.x, w1.y);
    smT[t * 5 + 3] = make_float2(w1.z, w1.w);
  }
  __syncthreads();

  // build Z(k) = T1(k) + i*T2(k) with Hermitian extension for k>128
  float2* a = smA[half];
  {
    float2 T1 = smT[lane * 5 + 2 * half], T2 = smT[lane * 5 + 2 * half + 1];
    a[lane] = make_float2(T1.x - T2.y, T1.y + T2.x);
    int km = (lane == 0) ? 128 : (128 - lane);
    float2 T1m = smT[km * 5 + 2 * half], T2m = smT[km * 5 + 2 * half + 1];
    a[lane + 128] = (lane == 0)
        ? make_float2(T1m.x - T2m.y, T1m.y + T2m.x)
        : make_float2(T1m.x + T2m.y, -T1m.y + T2m.x);
  }
  __syncthreads();
  float2* res = fft256t<1>(a, smB[half], lane, tw);  // rows y0+2h, y0+2h+1

  float* o0 = out + ((size_t)b * kS + y0 + 2 * half) * kS;
  float* o1 = o0 + kS;
  o0[lane]       = res[lane].x * (1.0f / 65536.0f);
  o0[lane + 128] = res[lane + 128].x * (1.0f / 65536.0f);
  o1[lane]       = res[lane].y * (1.0f / 65536.0f);
  o1[lane + 128] = res[lane + 128].y * (1.0f / 65536.0f);
}

// ---------------------------------------------------------------------------
extern "C" void kernel_launch(void* const* d_in, const int* in_sizes, int n_in,
                              void* d_out, int out_size, void* d_ws, size_t ws_size,
                              hipStream_t stream) {
  const float* c_nma        = (const float*)d_in[0];
  const float* delta_euler  = (const float*)d_in[1];
  const float* delta_shifts = (const float*)d_in[2];
  const float* coords       = (const float*)d_in[3];
  const float* basis_x      = (const float*)d_in[4];
  const float* basis_y      = (const float*)d_in[5];
  const float* basis_z      = (const float*)d_in[6];
  const float* euler_base   = (const float*)d_in[7];
  const float* shifts_base  = (const float*)d_in[8];
  const float* defocus      = (const float*)d_in[9];

  float* out = (float*)d_out;
  float* decoded = out;                                   // B*S*S
  float* bond    = out + (size_t)kB * kS * kS;            // B*(N-1)
  float* angle   = bond + (size_t)kB * (kN - 1);          // B*(N-2)

  char* ws = (char*)d_ws;
  const size_t imgBytes = (size_t)kB * kS * kS * sizeof(float);        // 8 MB
  float*    img    = (float*)ws;                           // [0, 8MB)
  unsigned* xy_bkt = (unsigned*)(ws + imgBytes);           // [8MB, 24MB) dead after k_splat
  float2*   FcT    = (float2*)(ws + imgBytes);             // [8MB, 16.5MB) aliases xy_bkt (after splat)
  int*      gcount = (int*)(ws + imgBytes + (size_t)17 * 1024 * 1024);  // [25MB, +16KB) padded
  float*    bnd    = (float*)(ws + imgBytes + (size_t)18 * 1024 * 1024);// [26MB, +229KB)

  k_zero<<<1, 256, 0, stream>>>(gcount);

  dim3 gd(kNB, kB / kBG);
  k_deform<<<gd, 256, 0, stream>>>(c_nma, delta_euler, delta_shifts, coords,
                                   basis_x, basis_y, basis_z, euler_base,
                                   shifts_base, xy_bkt, gcount, bond, angle);
  k_splat<<<kB * 8, 1024, 0, stream>>>(xy_bkt, gcount, img, bnd);
  k_fft_rows_fwd<<<kB * 64, 256, 0, stream>>>(img, bnd, FcT);
  k_fft_cols<<<kB * 65, 256, 0, stream>>>(FcT, defocus);
  k_fft_rows_inv<<<kB * 64, 256, 0, stream>>>(FcT, decoded);
}

// Round 12
// 71.733 us; speedup vs baseline: 1.0947x; 1.0080x over previous
//
#include <hip/hip_runtime.h>
#include <math.h>

namespace {
constexpr int kB = 32;
constexpr int kN = 100000;
constexpr int kL = 12;
constexpr int kS = 256;
constexpr int kBG = 8;                      // poses per block in deform kernel
constexpr int kWOwn = 62;                   // atoms OWNED per wave (2 shuffle-halo lanes)
constexpr int kTile = 4 * kWOwn;            // 248 atoms owned per 256-thread block
constexpr int kNB = (kN + kTile - 1) / kTile;  // 404 atom-blocks
constexpr int kCap = 16384;                 // per-(pose,band) bucket capacity
constexpr int kKx = 130;                    // stored kx columns (129 used + pad)
constexpr int kGPad = 16;                   // gcount stride in ints (64B = 1 line/counter)

constexpr float kGauss = (float)(2.0 * M_PI * M_PI);                         // 2(pi*sigma)^2, sigma=1
constexpr float kA1 = (float)(M_PI * 0.0197);                                // pi*lambda
constexpr float kA2 = (float)(0.5 * M_PI * 2.7e7 * 0.0197 * 0.0197 * 0.0197);// 0.5*pi*Cs*lambda^3
constexpr float kW1 = 0.99498743710661995f;                                  // sqrt(1-Q0^2)
constexpr float kQ0 = 0.1f;
}

// ---------------------------------------------------------------------------
// Zero the padded gcount array (256 counters * 16-int stride = 16 KB).
// ---------------------------------------------------------------------------
__global__ __launch_bounds__(256) void k_zero(int* __restrict__ gcount) {
  const int t = threadIdx.x;
#pragma unroll
  for (int i = 0; i < kB * 8 * kGPad / 256; ++i) gcount[i * 256 + t] = 0;
}

// ---------------------------------------------------------------------------
// 256-point Stockham radix-2 FFT in LDS with a shared twiddle table.
// 128 lanes per FFT, 8 stages, auto-sorting. Result ends in buffer `a`.
// tw[k] = (cos, sin)(pi*k/128); SIGN=-1 forward, +1 inverse.
// Contains __syncthreads(): ALL threads of the block must call uniformly
// (multiple 128-lane groups may run concurrent FFTs on their own buffers).
// ---------------------------------------------------------------------------
template <int SIGN>
__device__ __forceinline__ float2* fft256t(float2* a, float2* b, int lane,
                                           const float2* tw) {
#pragma unroll
  for (int m = 1; m <= 128; m <<= 1) {
    float2 c0 = a[lane];
    float2 c1 = a[lane + 128];
    int jm = lane & ~(m - 1);
    float2 w = tw[jm];
    float c = w.x;
    float s = (SIGN < 0) ? -w.y : w.y;
    float ex = c0.x + c1.x, ey = c0.y + c1.y;
    float dx = c0.x - c1.x, dy = c0.y - c1.y;
    b[lane + jm]     = make_float2(ex, ey);
    b[lane + jm + m] = make_float2(c * dx - s * dy, c * dy + s * dx);
    __syncthreads();
    float2* tp = a; a = b; b = tp;
  }
  return a;  // 8 swaps -> result back in original `a` buffer
}

__device__ __forceinline__ void build_tw(float2* tw, int t) {
  if (t < 128) {
    float s, c;
    sincosf((float)M_PI / 128.0f * (float)t, &s, &c);
    tw[t] = make_float2(c, s);
  }
}

// ---------------------------------------------------------------------------
// Phase A: deformation -> bond, angle, projected (x,y) packed u16.8 into
// per-(pose, 32-row band) compact bucket lists. Atoms whose bilinear
// footprint straddles a band boundary (y0 % 32 == 31) are DUPLICATED into
// the next band's bucket, so every band block owns its 32 rows completely
// (enables fused splat+rowFFT downstream; no img/bnd buffers).
// ---------------------------------------------------------------------------
__global__ __launch_bounds__(256) void k_deform(
    const float* __restrict__ c_nma, const float* __restrict__ delta_euler,
    const float* __restrict__ delta_shifts, const float* __restrict__ coords,
    const float* __restrict__ basis_x, const float* __restrict__ basis_y,
    const float* __restrict__ basis_z, const float* __restrict__ euler_base,
    const float* __restrict__ shifts_base,
    unsigned* __restrict__ xy_bkt, int* __restrict__ gcount,
    float* __restrict__ bond, float* __restrict__ angle) {
  __shared__ float cn_s[kBG][kL];
  __shared__ float rsh_s[kBG][8];
  __shared__ int bcnt[kBG][8];
  __shared__ int bbase[kBG][8];

  const int t = threadIdx.x;
  const int wave = t >> 6, lane = t & 63;
  const int bg = blockIdx.y * kBG;
  const int n = blockIdx.x * kTile + wave * kWOwn + lane;
  const bool owner = (lane < kWOwn) && (n < kN);
  const int nc = min(n, kN - 1);

  if (t < kBG * kL) cn_s[t / kL][t % kL] = c_nma[(bg + t / kL) * kL + (t % kL)];
  if (t < kBG) {
    int b = bg + t;
    float rot  = euler_base[b * 3 + 0] + delta_euler[b * 3 + 0];
    float tilt = euler_base[b * 3 + 1] + delta_euler[b * 3 + 1];
    float psi  = euler_base[b * 3 + 2] + delta_euler[b * 3 + 2];
    float ca = cosf(rot), sa = sinf(rot);
    float cb = cosf(tilt), sb = sinf(tilt);
    float cg = cosf(psi), sg = sinf(psi);
    rsh_s[t][0] = cg * cb * ca - sg * sa;
    rsh_s[t][1] = cg * cb * sa + sg * ca;
    rsh_s[t][2] = -cg * sb;
    rsh_s[t][3] = -sg * cb * ca - cg * sa;
    rsh_s[t][4] = -sg * cb * sa + cg * ca;
    rsh_s[t][5] = sg * sb;
    rsh_s[t][6] = shifts_base[b * 2 + 0] + delta_shifts[b * 2 + 0] + 128.0f;
    rsh_s[t][7] = shifts_base[b * 2 + 1] + delta_shifts[b * 2 + 1] + 128.0f;
  }
  if (t < kBG * 8) bcnt[t >> 3][t & 7] = 0;

  const float cx = coords[nc * 3 + 0];
  const float cy = coords[nc * 3 + 1];
  const float cz = coords[nc * 3 + 2];
  float bx[kL], by[kL], bz[kL];
  {
    const float4* px4 = reinterpret_cast<const float4*>(basis_x + (size_t)nc * kL);
    const float4* py4 = reinterpret_cast<const float4*>(basis_y + (size_t)nc * kL);
    const float4* pz4 = reinterpret_cast<const float4*>(basis_z + (size_t)nc * kL);
#pragma unroll
    for (int q = 0; q < 3; ++q) {
      float4 vx = px4[q], vy = py4[q], vz = pz4[q];
      bx[q * 4 + 0] = vx.x; bx[q * 4 + 1] = vx.y; bx[q * 4 + 2] = vx.z; bx[q * 4 + 3] = vx.w;
      by[q * 4 + 0] = vy.x; by[q * 4 + 1] = vy.y; by[q * 4 + 2] = vy.z; by[q * 4 + 3] = vy.w;
      bz[q * 4 + 0] = vz.x; bz[q * 4 + 1] = vz.y; bz[q * 4 + 2] = vz.z; bz[q * 4 + 3] = vz.w;
    }
  }
  __syncthreads();

  unsigned ureg[kBG];   // packed (y<<16)|x per pose
  unsigned meta[kBG];   // (rank<<3)|band per pose
  unsigned meta2[kBG];  // straddle duplicate: (rank2<<3)|band1, ~0u if none

#pragma unroll
  for (int bi = 0; bi < kBG; ++bi) {
    const int b = bg + bi;
    float px = cx, py = cy, pz = cz;
#pragma unroll
    for (int l = 0; l < kL; ++l) {
      float cc = cn_s[bi][l];
      px = fmaf(cc, bx[l], px);
      py = fmaf(cc, by[l], py);
      pz = fmaf(cc, bz[l], pz);
    }
    // neighbor deltas via wave shuffles (computed by all 64 lanes)
    float p1x = __shfl_down(px, 1), p1y = __shfl_down(py, 1), p1z = __shfl_down(pz, 1);
    float dx = p1x - px, dy = p1y - py, dz = p1z - pz;
    float dd = fmaf(dx, dx, fmaf(dy, dy, dz * dz));
    float d1x = __shfl_down(dx, 1), d1y = __shfl_down(dy, 1), d1z = __shfl_down(dz, 1);

    ureg[bi] = 0; meta[bi] = 0; meta2[bi] = ~0u;
    if (owner) {
      // projection; quantize to u16.8 fixed point (floor), pack (y<<16)|x
      float xr = fmaf(rsh_s[bi][0], px, fmaf(rsh_s[bi][1], py, fmaf(rsh_s[bi][2], pz, rsh_s[bi][6])));
      float yr = fmaf(rsh_s[bi][3], px, fmaf(rsh_s[bi][4], py, fmaf(rsh_s[bi][5], pz, rsh_s[bi][7])));
      xr = fminf(fmaxf(xr, 0.0f), 254.999f);
      yr = fminf(fmaxf(yr, 0.0f), 254.999f);
      unsigned xf = (unsigned)(xr * 256.0f);   // <= 65279 -> x0 <= 254
      unsigned yf = (unsigned)(yr * 256.0f);
      unsigned y0i = yf >> 8;                  // 0..254
      unsigned band = y0i >> 5;                // 0..7
      int rank = atomicAdd(&bcnt[bi][band], 1);
      ureg[bi] = (yf << 16) | xf;
      meta[bi] = ((unsigned)rank << 3) | band;
      if ((y0i & 31u) == 31u) {                // footprint straddles band edge
        unsigned band1 = band + 1;             // y0i<=223 here, so band1<=7
        int r2 = atomicAdd(&bcnt[bi][band1], 1);
        meta2[bi] = ((unsigned)r2 << 3) | band1;
      }
      // bond length at n (atoms n, n+1)
      if (n < kN - 1) {
        __builtin_nontemporal_store(sqrtf(dd + 1e-12f),
                                    &bond[(size_t)b * (kN - 1) + n]);
      }
      // angle at interior atom n+1 (u = -d, v = d1); fast acos
      if (n < kN - 2) {
        float vv = fmaf(d1x, d1x, fmaf(d1y, d1y, d1z * d1z));
        float uv = -fmaf(dx, d1x, fmaf(dy, d1y, dz * d1z));
        float cosang = uv * rsqrtf(dd * vv);
        cosang = fminf(fmaxf(cosang, -0.9999f), 0.9999f);
        float ax = fabsf(cosang);
        float rt = sqrtf(1.0f - ax);
        float pp = fmaf(fmaf(fmaf(-0.0187293f, ax, 0.0742610f), ax, -0.2121144f),
                        ax, 1.5707288f);
        float res = rt * pp;
        __builtin_nontemporal_store((cosang >= 0.f) ? res : (float)M_PI - res,
                                    &angle[(size_t)b * (kN - 2) + n]);
      }
    }
  }
  __syncthreads();
  if (t < kBG * 8) {
    int po = t >> 3, bandx = t & 7;
    int c = bcnt[po][bandx];
    bbase[po][bandx] =
        c ? atomicAdd(&gcount[((bg + po) * 8 + bandx) * kGPad], c) : 0;
  }
  __syncthreads();
#pragma unroll
  for (int bi = 0; bi < kBG; ++bi) {
    if (owner) {
      unsigned band = meta[bi] & 7;
      int pos = bbase[bi][band] + (int)(meta[bi] >> 3);
      if (pos < kCap) xy_bkt[((size_t)(bg + bi) * 8 + band) * kCap + pos] = ureg[bi];
      if (meta2[bi] != ~0u) {
        unsigned band1 = meta2[bi] & 7;
        int pos2 = bbase[bi][band1] + (int)(meta2[bi] >> 3);
        if (pos2 < kCap)
          xy_bkt[((size_t)(bg + bi) * 8 + band1) * kCap + pos2] = ureg[bi];
      }
    }
  }
}

// ---------------------------------------------------------------------------
// Phase B (FUSED): bilinear splat into a 32x256 u18.14 LDS tile (ds_add_u32)
// + 16 packed real row-FFTs in the same block, writing the Hermitian-reduced
// transposed spectrum FcT[b][kx][y] directly. No img round-trip, no bnd:
// straddle atoms were duplicated so each band owns its 32 rows completely.
// grid: 32 poses * 8 bands, 1024 threads (8 concurrent 128-lane FFTs x 2).
// ---------------------------------------------------------------------------
__global__ __launch_bounds__(1024) void k_splat_fft(
    const unsigned* __restrict__ xy_bkt, const int* __restrict__ gcount,
    float2* __restrict__ FcT) {
  __shared__ unsigned tile[32 * 256];
  __shared__ float2 smA[8][256];
  __shared__ float2 smB[8][256];
  __shared__ float2 tw[128];
  const int t = threadIdx.x;
  const int b = blockIdx.x >> 3;
  const int band = blockIdx.x & 7;
  const int r0 = band * 32;
  build_tw(tw, t);
  for (int i = t; i < 32 * 256; i += 1024) tile[i] = 0u;
  __syncthreads();

  const int c = min(gcount[(b * 8 + band) * kGPad], kCap);
  const unsigned* seg = xy_bkt + ((size_t)b * 8 + band) * kCap;

  auto splat1 = [&](unsigned u) {
    int yf = (int)(u >> 16);
    int xf = (int)(u & 0xFFFFu);
    int ry = (yf >> 8) - r0;                 // -1..31 (straddle dups land at -1)
    int x0 = xf >> 8;
    int fx = xf & 255, fy = yf & 255;        // u0.8 fractions
    int gx = 256 - fx, gy = 256 - fy;
    if ((unsigned)ry < 32u) {                // row y0: weight (1-fy)
      int base = ry * 256 + x0;
      atomicAdd(&tile[base],     (unsigned)((gx * gy + 2) >> 2));
      atomicAdd(&tile[base + 1], (unsigned)((fx * gy + 2) >> 2));
    }
    if ((unsigned)(ry + 1) < 32u) {          // row y0+1: weight fy
      int base = (ry + 1) * 256 + x0;
      atomicAdd(&tile[base],     (unsigned)((gx * fy + 2) >> 2));
      atomicAdd(&tile[base + 1], (unsigned)((fx * fy + 2) >> 2));
    }
  };

  const int c4 = c & ~3;
  const uint4* seg4 = reinterpret_cast<const uint4*>(seg);
  for (int i4 = t; i4 * 4 < c4; i4 += 1024) {
    uint4 q = seg4[i4];
    splat1(q.x); splat1(q.y); splat1(q.z); splat1(q.w);
  }
  for (int i = c4 + t; i < c; i += 1024) splat1(seg[i]);
  __syncthreads();

  // 32 rows = 16 packed pairs; 8 groups of 128 lanes x 2 iterations.
  const int g = t >> 7, gl = t & 127;
  constexpr float scale = 1.0f / 16384.0f;
#pragma unroll
  for (int iter = 0; iter < 2; ++iter) {
    const int p = iter * 8 + g;              // pair index 0..15
    const int rowA = 2 * p;                  // rows rowA, rowA+1 (in tile)
    float2* a = smA[g];
    a[gl] = make_float2((float)tile[rowA * 256 + gl] * scale,
                        (float)tile[(rowA + 1) * 256 + gl] * scale);
    a[gl + 128] = make_float2((float)tile[rowA * 256 + gl + 128] * scale,
                              (float)tile[(rowA + 1) * 256 + gl + 128] * scale);
    float2* res = fft256t<-1>(a, smB[g], gl, tw);
    // unpack two real row-spectra at k and write float4 (covers y, y+1)
    const int y = r0 + rowA;
    {
      int tm = (256 - gl) & 255;
      float2 Zk = res[gl], Zm = res[tm];
      float4 o = make_float4(0.5f * (Zk.x + Zm.x), 0.5f * (Zk.y - Zm.y),
                             0.5f * (Zk.y + Zm.y), 0.5f * (Zm.x - Zk.x));
      *reinterpret_cast<float4*>(&FcT[((size_t)b * kKx + gl) * kS + y]) = o;
    }
    if (gl == 0) {                           // k = 128 (Nyquist)
      float2 Zk = res[128];
      float4 o = make_float4(Zk.x, 0.f, Zk.y, 0.f);
      *reinterpret_cast<float4*>(&FcT[((size_t)b * kKx + 128) * kS + y]) = o;
    }
    __syncthreads();                         // unpack reads done before reuse
  }
}

// ---------------------------------------------------------------------------
// Column FFT * H * inverse column FFT on the Hermitian-reduced spectrum.
// ---------------------------------------------------------------------------
__global__ __launch_bounds__(256) void k_fft_cols(float2* __restrict__ FcT,
                                                  const float* __restrict__ defocus) {
  __shared__ float2 sm[4][256];
  __shared__ float2 tw[128];
  const int t = threadIdx.x, half = t >> 7, lane = t & 127;
  build_tw(tw, t);
  const int b = blockIdx.x / 65, kxp = blockIdx.x % 65;
  const int kx = kxp * 2 + half;          // 0..129; 129 is duplicate work
  const int kxr = min(kx, 128);
  float2* col = FcT + ((size_t)b * kKx + kxr) * kS;   // contiguous column
  float2* a = sm[half * 2];
  float2* bb = sm[half * 2 + 1];
  __syncthreads();
  a[lane]       = col[lane];
  a[lane + 128] = col[lane + 128];
  float2* r1 = fft256t<-1>(a, bb, lane, tw);

  // apply real filter H(ky,kx) = G * CTF (defocus-dependent per pose)
  const float D = defocus[b];
  const float fxv = (float)kxr * (1.0f / 256.0f);     // rfftfreq: 0..0.5
  const float fx2 = fxv * fxv;
#pragma unroll
  for (int h = 0; h < 2; ++h) {
    int ky = lane + h * 128;
    float fyv = (float)(ky < 128 ? ky : ky - 256) * (1.0f / 256.0f);
    float s2 = fyv * fyv + fx2;
    float G = __expf(-kGauss * s2);
    float chi = kA1 * D * s2 - kA2 * s2 * s2;
    float sn, cn;
    sincosf(chi, &sn, &cn);
    float H = G * (-(kW1 * sn + kQ0 * cn));
    r1[ky].x *= H;
    r1[ky].y *= H;
  }
  float2* r2 = (r1 == a) ? bb : a;
  float2* res = fft256t<1>(r1, r2, lane, tw);
  if (kx <= 128) {
    col[lane]       = res[lane];
    col[lane + 128] = res[lane + 128];
  }
}

__global__ __launch_bounds__(256) void k_fft_rows_inv(const float2* __restrict__ FcT,
                                                      float* __restrict__ out) {
  __shared__ float2 smA[2][256];
  __shared__ float2 smB[2][256];
  __shared__ float2 smT[130 * 5];          // [k][r], stride 5 to spread banks
  __shared__ float2 tw[128];
  const int t = threadIdx.x, half = t >> 7, lane = t & 127;
  build_tw(tw, t);
  const int b = blockIdx.x >> 6;
  const int y0 = (blockIdx.x & 63) * 4;

  // stage T(k, y0..y0+3), k = 0..128 (transpose read, 32B chunks)
  if (t < 129) {
    const float4* ip =
        reinterpret_cast<const float4*>(FcT + ((size_t)b * kKx + t) * kS + y0);
    float4 w0 = ip[0], w1 = ip[1];
    smT[t * 5 + 0] = make_float2(w0.x, w0.y);
    smT[t * 5 + 1] = make_float2(w0.z, w0.w);
    smT[t * 5 + 2] = make_float2(w1.x, w1.y);
    smT[t * 5 + 3] = make_float2(w1.z, w1.w);
  }
  __syncthreads();

  // build Z(k) = T1(k) + i*T2(k) with Hermitian extension for k>128
  float2* a = smA[half];
  {
    float2 T1 = smT[lane * 5 + 2 * half], T2 = smT[lane * 5 + 2 * half + 1];
    a[lane] = make_float2(T1.x - T2.y, T1.y + T2.x);
    int km = (lane == 0) ? 128 : (128 - lane);
    float2 T1m = smT[km * 5 + 2 * half], T2m = smT[km * 5 + 2 * half + 1];
    a[lane + 128] = (lane == 0)
        ? make_float2(T1m.x - T2m.y, T1m.y + T2m.x)
        : make_float2(T1m.x + T2m.y, -T1m.y + T2m.x);
  }
  __syncthreads();
  float2* res = fft256t<1>(a, smB[half], lane, tw);  // rows y0+2h, y0+2h+1

  float* o0 = out + ((size_t)b * kS + y0 + 2 * half) * kS;
  float* o1 = o0 + kS;
  o0[lane]       = res[lane].x * (1.0f / 65536.0f);
  o0[lane + 128] = res[lane + 128].x * (1.0f / 65536.0f);
  o1[lane]       = res[lane].y * (1.0f / 65536.0f);
  o1[lane + 128] = res[lane + 128].y * (1.0f / 65536.0f);
}

// ---------------------------------------------------------------------------
extern "C" void kernel_launch(void* const* d_in, const int* in_sizes, int n_in,
                              void* d_out, int out_size, void* d_ws, size_t ws_size,
                              hipStream_t stream) {
  const float* c_nma        = (const float*)d_in[0];
  const float* delta_euler  = (const float*)d_in[1];
  const float* delta_shifts = (const float*)d_in[2];
  const float* coords       = (const float*)d_in[3];
  const float* basis_x      = (const float*)d_in[4];
  const float* basis_y      = (const float*)d_in[5];
  const float* basis_z      = (const float*)d_in[6];
  const float* euler_base   = (const float*)d_in[7];
  const float* shifts_base  = (const float*)d_in[8];
  const float* defocus      = (const float*)d_in[9];

  float* out = (float*)d_out;
  float* decoded = out;                                   // B*S*S
  float* bond    = out + (size_t)kB * kS * kS;            // B*(N-1)
  float* angle   = bond + (size_t)kB * (kN - 1);          // B*(N-2)

  char* ws = (char*)d_ws;
  unsigned* xy_bkt = (unsigned*)ws;                              // [0, 16MB)
  float2*   FcT    = (float2*)(ws + (size_t)16 * 1024 * 1024);   // [16MB, 24.5MB)
  int*      gcount = (int*)(ws + (size_t)25 * 1024 * 1024);      // [25MB, +16KB)

  k_zero<<<1, 256, 0, stream>>>(gcount);

  dim3 gd(kNB, kB / kBG);
  k_deform<<<gd, 256, 0, stream>>>(c_nma, delta_euler, delta_shifts, coords,
                                   basis_x, basis_y, basis_z, euler_base,
                                   shifts_base, xy_bkt, gcount, bond, angle);
  k_splat_fft<<<kB * 8, 1024, 0, stream>>>(xy_bkt, gcount, FcT);
  k_fft_cols<<<kB * 65, 256, 0, stream>>>(FcT, defocus);
  k_fft_rows_inv<<<kB * 64, 256, 0, stream>>>(FcT, decoded);
}

// Round 13
// 65.797 us; speedup vs baseline: 1.1934x; 1.0902x over previous
//
#include <hip/hip_runtime.h>
#include <math.h>

namespace {
constexpr int kB = 32;
constexpr int kN = 100000;
constexpr int kL = 12;
constexpr int kS = 256;
constexpr int kBG = 8;                      // poses per block in deform kernel
constexpr int kWOwn = 62;                   // atoms OWNED per wave (2 shuffle-halo lanes)
constexpr int kTile = 4 * kWOwn;            // 248 atoms owned per 256-thread block
constexpr int kNB = (kN + kTile - 1) / kTile;  // 404 atom-blocks
constexpr int kCap = 16384;                 // per-(pose,band) bucket capacity
constexpr int kKx = 130;                    // stored kx columns (129 used + pad)
constexpr int kGPad = 16;                   // gcount stride in ints (64B = 1 line/counter)

constexpr float kGauss = (float)(2.0 * M_PI * M_PI);                         // 2(pi*sigma)^2, sigma=1
constexpr float kA1 = (float)(M_PI * 0.0197);                                // pi*lambda
constexpr float kA2 = (float)(0.5 * M_PI * 2.7e7 * 0.0197 * 0.0197 * 0.0197);// 0.5*pi*Cs*lambda^3
constexpr float kW1 = 0.99498743710661995f;                                  // sqrt(1-Q0^2)
constexpr float kQ0 = 0.1f;
}

// ---------------------------------------------------------------------------
// Zero the padded gcount array (256 counters * 16-int stride = 16 KB).
// ---------------------------------------------------------------------------
__global__ __launch_bounds__(256) void k_zero(int* __restrict__ gcount) {
  const int t = threadIdx.x;
#pragma unroll
  for (int i = 0; i < kB * 8 * kGPad / 256; ++i) gcount[i * 256 + t] = 0;
}

__device__ __forceinline__ void build_tw(float2* tw, int t) {
  if (t < 128) {
    float s, c;
    sincosf((float)M_PI / 128.0f * (float)t, &s, &c);
    tw[t] = make_float2(c, s);
  }
}

// ---------------------------------------------------------------------------
// PER-WAVE 256-point Stockham radix-4 FFT: 64 lanes, 4 float2 regs/lane,
// 4 stages (m = 1,4,16,64), single 256-float2 LDS work buffer, NO barriers
// (one wave owns the FFT; per-wave LDS ordering guarantees RAW).
// Derived by composing two verified radix-2 Stockham stages (m, 2m):
//   y[u*4m+l+{0,m,2m,3m}] = {S, w*(d02+sgn*i*d13), w^2*(s02-s13), w^3*(...)}
// with w = tw[u*m] (angle pi*jm/128), sign via conjugation. Input/output:
// v[j] = x[lane + 64*j], natural order (Stockham autosort).
// ---------------------------------------------------------------------------
template <int SIGN>
__device__ __forceinline__ void fft256w(float2 v[4], float2* fb, int lane,
                                        const float2* tw) {
#pragma unroll
  for (int m = 1; m <= 64; m *= 4) {
    int l = lane & (m - 1);
    int jm = lane - l;                 // u*m
    float2 wv = tw[jm];
    float c = wv.x;
    float s = (SIGN < 0) ? -wv.y : wv.y;
    float2 A0 = v[0], A1 = v[1], A2 = v[2], A3 = v[3];
    float s02x = A0.x + A2.x, s02y = A0.y + A2.y;
    float d02x = A0.x - A2.x, d02y = A0.y - A2.y;
    float s13x = A1.x + A3.x, s13y = A1.y + A3.y;
    float d13x = A1.x - A3.x, d13y = A1.y - A3.y;
    float jdx = (SIGN < 0) ? d13y : -d13y;      // sgn*i*(d13)
    float jdy = (SIGN < 0) ? -d13x : d13x;
    float t1x = d02x + jdx, t1y = d02y + jdy;
    float t2x = s02x - s13x, t2y = s02y - s13y;
    float t3x = d02x - jdx, t3y = d02y - jdy;
    float c2 = c * c - s * s, s2 = 2.f * c * s;
    float c3 = c2 * c - s2 * s, s3 = c2 * s + s2 * c;
    int ob = 4 * jm + l;
    fb[ob]         = make_float2(s02x + s13x, s02y + s13y);
    fb[ob + m]     = make_float2(c * t1x - s * t1y, c * t1y + s * t1x);
    fb[ob + 2 * m] = make_float2(c2 * t2x - s2 * t2y, c2 * t2y + s2 * t2x);
    fb[ob + 3 * m] = make_float2(c3 * t3x - s3 * t3y, c3 * t3y + s3 * t3x);
    v[0] = fb[lane];
    v[1] = fb[lane + 64];
    v[2] = fb[lane + 128];
    v[3] = fb[lane + 192];
  }
}

// ---------------------------------------------------------------------------
// Phase A: deformation -> bond, angle, projected (x,y) packed u16.8 into
// per-(pose, 32-row band) compact bucket lists. Straddle atoms (y0%32==31)
// are duplicated into the next band so each band owns its 32 rows fully.
// (unchanged from round 12)
// ---------------------------------------------------------------------------
__global__ __launch_bounds__(256) void k_deform(
    const float* __restrict__ c_nma, const float* __restrict__ delta_euler,
    const float* __restrict__ delta_shifts, const float* __restrict__ coords,
    const float* __restrict__ basis_x, const float* __restrict__ basis_y,
    const float* __restrict__ basis_z, const float* __restrict__ euler_base,
    const float* __restrict__ shifts_base,
    unsigned* __restrict__ xy_bkt, int* __restrict__ gcount,
    float* __restrict__ bond, float* __restrict__ angle) {
  __shared__ float cn_s[kBG][kL];
  __shared__ float rsh_s[kBG][8];
  __shared__ int bcnt[kBG][8];
  __shared__ int bbase[kBG][8];

  const int t = threadIdx.x;
  const int wave = t >> 6, lane = t & 63;
  const int bg = blockIdx.y * kBG;
  const int n = blockIdx.x * kTile + wave * kWOwn + lane;
  const bool owner = (lane < kWOwn) && (n < kN);
  const int nc = min(n, kN - 1);

  if (t < kBG * kL) cn_s[t / kL][t % kL] = c_nma[(bg + t / kL) * kL + (t % kL)];
  if (t < kBG) {
    int b = bg + t;
    float rot  = euler_base[b * 3 + 0] + delta_euler[b * 3 + 0];
    float tilt = euler_base[b * 3 + 1] + delta_euler[b * 3 + 1];
    float psi  = euler_base[b * 3 + 2] + delta_euler[b * 3 + 2];
    float ca = cosf(rot), sa = sinf(rot);
    float cb = cosf(tilt), sb = sinf(tilt);
    float cg = cosf(psi), sg = sinf(psi);
    rsh_s[t][0] = cg * cb * ca - sg * sa;
    rsh_s[t][1] = cg * cb * sa + sg * ca;
    rsh_s[t][2] = -cg * sb;
    rsh_s[t][3] = -sg * cb * ca - cg * sa;
    rsh_s[t][4] = -sg * cb * sa + cg * ca;
    rsh_s[t][5] = sg * sb;
    rsh_s[t][6] = shifts_base[b * 2 + 0] + delta_shifts[b * 2 + 0] + 128.0f;
    rsh_s[t][7] = shifts_base[b * 2 + 1] + delta_shifts[b * 2 + 1] + 128.0f;
  }
  if (t < kBG * 8) bcnt[t >> 3][t & 7] = 0;

  const float cx = coords[nc * 3 + 0];
  const float cy = coords[nc * 3 + 1];
  const float cz = coords[nc * 3 + 2];
  float bx[kL], by[kL], bz[kL];
  {
    const float4* px4 = reinterpret_cast<const float4*>(basis_x + (size_t)nc * kL);
    const float4* py4 = reinterpret_cast<const float4*>(basis_y + (size_t)nc * kL);
    const float4* pz4 = reinterpret_cast<const float4*>(basis_z + (size_t)nc * kL);
#pragma unroll
    for (int q = 0; q < 3; ++q) {
      float4 vx = px4[q], vy = py4[q], vz = pz4[q];
      bx[q * 4 + 0] = vx.x; bx[q * 4 + 1] = vx.y; bx[q * 4 + 2] = vx.z; bx[q * 4 + 3] = vx.w;
      by[q * 4 + 0] = vy.x; by[q * 4 + 1] = vy.y; by[q * 4 + 2] = vy.z; by[q * 4 + 3] = vy.w;
      bz[q * 4 + 0] = vz.x; bz[q * 4 + 1] = vz.y; bz[q * 4 + 2] = vz.z; bz[q * 4 + 3] = vz.w;
    }
  }
  __syncthreads();

  unsigned ureg[kBG];   // packed (y<<16)|x per pose
  unsigned meta[kBG];   // (rank<<3)|band per pose
  unsigned meta2[kBG];  // straddle duplicate: (rank2<<3)|band1, ~0u if none

#pragma unroll
  for (int bi = 0; bi < kBG; ++bi) {
    const int b = bg + bi;
    float px = cx, py = cy, pz = cz;
#pragma unroll
    for (int l = 0; l < kL; ++l) {
      float cc = cn_s[bi][l];
      px = fmaf(cc, bx[l], px);
      py = fmaf(cc, by[l], py);
      pz = fmaf(cc, bz[l], pz);
    }
    float p1x = __shfl_down(px, 1), p1y = __shfl_down(py, 1), p1z = __shfl_down(pz, 1);
    float dx = p1x - px, dy = p1y - py, dz = p1z - pz;
    float dd = fmaf(dx, dx, fmaf(dy, dy, dz * dz));
    float d1x = __shfl_down(dx, 1), d1y = __shfl_down(dy, 1), d1z = __shfl_down(dz, 1);

    ureg[bi] = 0; meta[bi] = 0; meta2[bi] = ~0u;
    if (owner) {
      float xr = fmaf(rsh_s[bi][0], px, fmaf(rsh_s[bi][1], py, fmaf(rsh_s[bi][2], pz, rsh_s[bi][6])));
      float yr = fmaf(rsh_s[bi][3], px, fmaf(rsh_s[bi][4], py, fmaf(rsh_s[bi][5], pz, rsh_s[bi][7])));
      xr = fminf(fmaxf(xr, 0.0f), 254.999f);
      yr = fminf(fmaxf(yr, 0.0f), 254.999f);
      unsigned xf = (unsigned)(xr * 256.0f);   // <= 65279 -> x0 <= 254
      unsigned yf = (unsigned)(yr * 256.0f);
      unsigned y0i = yf >> 8;                  // 0..254
      unsigned band = y0i >> 5;                // 0..7
      int rank = atomicAdd(&bcnt[bi][band], 1);
      ureg[bi] = (yf << 16) | xf;
      meta[bi] = ((unsigned)rank << 3) | band;
      if ((y0i & 31u) == 31u) {                // footprint straddles band edge
        unsigned band1 = band + 1;
        int r2 = atomicAdd(&bcnt[bi][band1], 1);
        meta2[bi] = ((unsigned)r2 << 3) | band1;
      }
      if (n < kN - 1) {
        __builtin_nontemporal_store(sqrtf(dd + 1e-12f),
                                    &bond[(size_t)b * (kN - 1) + n]);
      }
      if (n < kN - 2) {
        float vv = fmaf(d1x, d1x, fmaf(d1y, d1y, d1z * d1z));
        float uv = -fmaf(dx, d1x, fmaf(dy, d1y, dz * d1z));
        float cosang = uv * rsqrtf(dd * vv);
        cosang = fminf(fmaxf(cosang, -0.9999f), 0.9999f);
        float ax = fabsf(cosang);
        float rt = sqrtf(1.0f - ax);
        float pp = fmaf(fmaf(fmaf(-0.0187293f, ax, 0.0742610f), ax, -0.2121144f),
                        ax, 1.5707288f);
        float res = rt * pp;
        __builtin_nontemporal_store((cosang >= 0.f) ? res : (float)M_PI - res,
                                    &angle[(size_t)b * (kN - 2) + n]);
      }
    }
  }
  __syncthreads();
  if (t < kBG * 8) {
    int po = t >> 3, bandx = t & 7;
    int c = bcnt[po][bandx];
    bbase[po][bandx] =
        c ? atomicAdd(&gcount[((bg + po) * 8 + bandx) * kGPad], c) : 0;
  }
  __syncthreads();
#pragma unroll
  for (int bi = 0; bi < kBG; ++bi) {
    if (owner) {
      unsigned band = meta[bi] & 7;
      int pos = bbase[bi][band] + (int)(meta[bi] >> 3);
      if (pos < kCap) xy_bkt[((size_t)(bg + bi) * 8 + band) * kCap + pos] = ureg[bi];
      if (meta2[bi] != ~0u) {
        unsigned band1 = meta2[bi] & 7;
        int pos2 = bbase[bi][band1] + (int)(meta2[bi] >> 3);
        if (pos2 < kCap)
          xy_bkt[((size_t)(bg + bi) * 8 + band1) * kCap + pos2] = ureg[bi];
      }
    }
  }
}

// ---------------------------------------------------------------------------
// Phase B (FUSED): splat into 32x256 u18.14 LDS tile + 16 per-wave packed
// real row-FFTs (one wave per row-pair, barrier-free FFT), writing the
// Hermitian-reduced transposed spectrum FcT[b][kx][y] directly.
// grid: 32 poses * 8 bands, 1024 threads.
// ---------------------------------------------------------------------------
__global__ __launch_bounds__(1024) void k_splat_fft(
    const unsigned* __restrict__ xy_bkt, const int* __restrict__ gcount,
    float2* __restrict__ FcT) {
  __shared__ unsigned tile[32 * 256];
  __shared__ float2 fbuf[16][256];
  __shared__ float2 tw[128];
  const int t = threadIdx.x;
  const int b = blockIdx.x >> 3;
  const int band = blockIdx.x & 7;
  const int r0 = band * 32;
  build_tw(tw, t);
  for (int i = t; i < 32 * 256; i += 1024) tile[i] = 0u;
  __syncthreads();

  const int c = min(gcount[(b * 8 + band) * kGPad], kCap);
  const unsigned* seg = xy_bkt + ((size_t)b * 8 + band) * kCap;

  auto splat1 = [&](unsigned u) {
    int yf = (int)(u >> 16);
    int xf = (int)(u & 0xFFFFu);
    int ry = (yf >> 8) - r0;                 // -1..31 (straddle dups at -1)
    int x0 = xf >> 8;
    int fx = xf & 255, fy = yf & 255;
    int gx = 256 - fx, gy = 256 - fy;
    if ((unsigned)ry < 32u) {
      int base = ry * 256 + x0;
      atomicAdd(&tile[base],     (unsigned)((gx * gy + 2) >> 2));
      atomicAdd(&tile[base + 1], (unsigned)((fx * gy + 2) >> 2));
    }
    if ((unsigned)(ry + 1) < 32u) {
      int base = (ry + 1) * 256 + x0;
      atomicAdd(&tile[base],     (unsigned)((gx * fy + 2) >> 2));
      atomicAdd(&tile[base + 1], (unsigned)((fx * fy + 2) >> 2));
    }
  };

  const int c4 = c & ~3;
  const uint4* seg4 = reinterpret_cast<const uint4*>(seg);
  for (int i4 = t; i4 * 4 < c4; i4 += 1024) {
    uint4 q = seg4[i4];
    splat1(q.x); splat1(q.y); splat1(q.z); splat1(q.w);
  }
  for (int i = c4 + t; i < c; i += 1024) splat1(seg[i]);
  __syncthreads();

  // one wave per row-pair: rows 2w, 2w+1 packed as re+i*im
  const int w = t >> 6, lane = t & 63;
  const int rowA = 2 * w;
  constexpr float scale = 1.0f / 16384.0f;
  float2 v[4];
#pragma unroll
  for (int j = 0; j < 4; ++j) {
    int i = lane + 64 * j;
    v[j] = make_float2((float)tile[rowA * 256 + i] * scale,
                       (float)tile[(rowA + 1) * 256 + i] * scale);
  }
  fft256w<-1>(v, fbuf[w], lane, tw);
  float2* a = fbuf[w];                        // holds all 256 spectrum values
  const int y = r0 + rowA;
#pragma unroll
  for (int j = 0; j < 2; ++j) {
    int k = lane + 64 * j;
    float2 Zk = a[k], Zm = a[(256 - k) & 255];
    float4 o = make_float4(0.5f * (Zk.x + Zm.x), 0.5f * (Zk.y - Zm.y),
                           0.5f * (Zk.y + Zm.y), 0.5f * (Zm.x - Zk.x));
    *reinterpret_cast<float4*>(&FcT[((size_t)b * kKx + k) * kS + y]) = o;
  }
  if (lane == 0) {                            // Nyquist k=128
    float2 Zk = a[128];
    *reinterpret_cast<float4*>(&FcT[((size_t)b * kKx + 128) * kS + y]) =
        make_float4(Zk.x, 0.f, Zk.y, 0.f);
  }
}

// ---------------------------------------------------------------------------
// Column FFT * H * inverse column FFT; one wave per (pose, kx) column.
// grid: 32 poses * 33 blocks (4 cols/block); kx > 128 waves exit early.
// ---------------------------------------------------------------------------
__global__ __launch_bounds__(256) void k_fft_cols(float2* __restrict__ FcT,
                                                  const float* __restrict__ defocus) {
  __shared__ float2 fbuf[4][256];
  __shared__ float2 tw[128];
  const int t = threadIdx.x, w = t >> 6, lane = t & 63;
  build_tw(tw, t);
  const int b = blockIdx.x / 33;
  const int kx = (blockIdx.x % 33) * 4 + w;
  __syncthreads();                            // tw ready
  if (kx > 128) return;
  float2* col = FcT + ((size_t)b * kKx + kx) * kS;
  float2 v[4];
#pragma unroll
  for (int j = 0; j < 4; ++j) v[j] = col[lane + 64 * j];
  fft256w<-1>(v, fbuf[w], lane, tw);

  const float D = defocus[b];
  const float fxv = (float)kx * (1.0f / 256.0f);
  const float fx2 = fxv * fxv;
#pragma unroll
  for (int j = 0; j < 4; ++j) {
    int ky = lane + 64 * j;
    float fyv = (float)(ky < 128 ? ky : ky - 256) * (1.0f / 256.0f);
    float s2 = fyv * fyv + fx2;
    float G = __expf(-kGauss * s2);
    float chi = kA1 * D * s2 - kA2 * s2 * s2;
    float sn, cn;
    sincosf(chi, &sn, &cn);
    float H = G * (-(kW1 * sn + kQ0 * cn));
    v[j].x *= H;
    v[j].y *= H;
  }
  fft256w<1>(v, fbuf[w], lane, tw);
#pragma unroll
  for (int j = 0; j < 4; ++j) col[lane + 64 * j] = v[j];
}

// ---------------------------------------------------------------------------
// Inverse row FFT: one wave per row-pair (y=2p, 2p+1). Hermitian-extend the
// 129 stored kx into the full 256-pt spectrum per wave, then barrier-free
// inverse FFT; real parts -> two output rows. grid: 32 poses * 32 blocks.
// ---------------------------------------------------------------------------
__global__ __launch_bounds__(256) void k_fft_rows_inv(const float2* __restrict__ FcT,
                                                      float* __restrict__ out) {
  __shared__ float2 fbuf[4][256];
  __shared__ float4 smT[4][132];
  __shared__ float2 tw[128];
  const int t = threadIdx.x, w = t >> 6, lane = t & 63;
  build_tw(tw, t);
  const int b = blockIdx.x >> 5;
  const int pp = (blockIdx.x & 31) * 4 + w;   // pair 0..127
  const int y = 2 * pp;

  const float4* Fp = reinterpret_cast<const float4*>(FcT + (size_t)b * kKx * kS + y);
  const size_t kstep = kS / 2;                // float4s between consecutive k
  smT[w][lane]      = Fp[(size_t)lane * kstep];
  smT[w][lane + 64] = Fp[(size_t)(lane + 64) * kstep];
  if (lane == 0) smT[w][128] = Fp[(size_t)128 * kstep];
  __syncthreads();                            // tw ready (smT is per-wave)

  float2 v[4];
  {
    float4 f = smT[w][lane];
    v[0] = make_float2(f.x - f.w, f.y + f.z);
  }
  {
    float4 f = smT[w][lane + 64];
    v[1] = make_float2(f.x - f.w, f.y + f.z);
  }
  if (lane == 0) {
    float4 f = smT[w][128];
    v[2] = make_float2(f.x - f.w, f.y + f.z);
  } else {
    float4 f = smT[w][128 - lane];            // Hermitian: k=128+lane
    v[2] = make_float2(f.x + f.w, -f.y + f.z);
  }
  {
    float4 f = smT[w][64 - lane];             // Hermitian: k=192+lane
    v[3] = make_float2(f.x + f.w, -f.y + f.z);
  }
  fft256w<1>(v, fbuf[w], lane, tw);

  float* o0 = out + ((size_t)b * kS + y) * kS;
  float* o1 = o0 + kS;
#pragma unroll
  for (int j = 0; j < 4; ++j) {
    int i = lane + 64 * j;
    o0[i] = v[j].x * (1.0f / 65536.0f);
    o1[i] = v[j].y * (1.0f / 65536.0f);
  }
}

// ---------------------------------------------------------------------------
extern "C" void kernel_launch(void* const* d_in, const int* in_sizes, int n_in,
                              void* d_out, int out_size, void* d_ws, size_t ws_size,
                              hipStream_t stream) {
  const float* c_nma        = (const float*)d_in[0];
  const float* delta_euler  = (const float*)d_in[1];
  const float* delta_shifts = (const float*)d_in[2];
  const float* coords       = (const float*)d_in[3];
  const float* basis_x      = (const float*)d_in[4];
  const float* basis_y      = (const float*)d_in[5];
  const float* basis_z      = (const float*)d_in[6];
  const float* euler_base   = (const float*)d_in[7];
  const float* shifts_base  = (const float*)d_in[8];
  const float* defocus      = (const float*)d_in[9];

  float* out = (float*)d_out;
  float* decoded = out;                                   // B*S*S
  float* bond    = out + (size_t)kB * kS * kS;            // B*(N-1)
  float* angle   = bond + (size_t)kB * (kN - 1);          // B*(N-2)

  char* ws = (char*)d_ws;
  unsigned* xy_bkt = (unsigned*)ws;                              // [0, 16MB)
  float2*   FcT    = (float2*)(ws + (size_t)16 * 1024 * 1024);   // [16MB, 24.5MB)
  int*      gcount = (int*)(ws + (size_t)25 * 1024 * 1024);      // [25MB, +16KB)

  k_zero<<<1, 256, 0, stream>>>(gcount);

  dim3 gd(kNB, kB / kBG);
  k_deform<<<gd, 256, 0, stream>>>(c_nma, delta_euler, delta_shifts, coords,
                                   basis_x, basis_y, basis_z, euler_base,
                                   shifts_base, xy_bkt, gcount, bond, angle);
  k_splat_fft<<<kB * 8, 1024, 0, stream>>>(xy_bkt, gcount, FcT);
  k_fft_cols<<<kB * 33, 256, 0, stream>>>(FcT, defocus);
  k_fft_rows_inv<<<kB * 32, 256, 0, stream>>>(FcT, decoded);
}

// Round 14
// 57.346 us; speedup vs baseline: 1.3693x; 1.1474x over previous
//
#include <hip/hip_runtime.h>
#include <math.h>

namespace {
constexpr int kB = 32;
constexpr int kN = 100000;
constexpr int kL = 12;
constexpr int kS = 256;
constexpr int kBG = 8;                      // poses per block in deform kernel
constexpr int kWOwn = 62;                   // atoms OWNED per wave (2 shuffle-halo lanes)
constexpr int kTile = 4 * kWOwn;            // 248 atoms owned per 256-thread block
constexpr int kNB = (kN + kTile - 1) / kTile;  // 404 atom-blocks
constexpr int kSlot = 64;                   // slots per (pose, band, source-block)
constexpr int kKx = 130;                    // stored kx columns (129 used + pad)

constexpr float kGauss = (float)(2.0 * M_PI * M_PI);                         // 2(pi*sigma)^2, sigma=1
constexpr float kA1 = (float)(M_PI * 0.0197);                                // pi*lambda
constexpr float kA2 = (float)(0.5 * M_PI * 2.7e7 * 0.0197 * 0.0197 * 0.0197);// 0.5*pi*Cs*lambda^3
constexpr float kW1 = 0.99498743710661995f;                                  // sqrt(1-Q0^2)
constexpr float kQ0 = 0.1f;
}

__device__ __forceinline__ void build_tw(float2* tw, int t) {
  if (t < 128) {
    float s, c;
    sincosf((float)M_PI / 128.0f * (float)t, &s, &c);
    tw[t] = make_float2(c, s);
  }
}

// ---------------------------------------------------------------------------
// PER-WAVE 256-point Stockham radix-4 FFT: 64 lanes, 4 float2 regs/lane,
// 4 stages (m = 1,4,16,64), single 256-float2 LDS work buffer, NO barriers.
// ---------------------------------------------------------------------------
template <int SIGN>
__device__ __forceinline__ void fft256w(float2 v[4], float2* fb, int lane,
                                        const float2* tw) {
#pragma unroll
  for (int m = 1; m <= 64; m *= 4) {
    int l = lane & (m - 1);
    int jm = lane - l;                 // u*m
    float2 wv = tw[jm];
    float c = wv.x;
    float s = (SIGN < 0) ? -wv.y : wv.y;
    float2 A0 = v[0], A1 = v[1], A2 = v[2], A3 = v[3];
    float s02x = A0.x + A2.x, s02y = A0.y + A2.y;
    float d02x = A0.x - A2.x, d02y = A0.y - A2.y;
    float s13x = A1.x + A3.x, s13y = A1.y + A3.y;
    float d13x = A1.x - A3.x, d13y = A1.y - A3.y;
    float jdx = (SIGN < 0) ? d13y : -d13y;      // sgn*i*(d13)
    float jdy = (SIGN < 0) ? -d13x : d13x;
    float t1x = d02x + jdx, t1y = d02y + jdy;
    float t2x = s02x - s13x, t2y = s02y - s13y;
    float t3x = d02x - jdx, t3y = d02y - jdy;
    float c2 = c * c - s * s, s2 = 2.f * c * s;
    float c3 = c2 * c - s2 * s, s3 = c2 * s + s2 * c;
    int ob = 4 * jm + l;
    fb[ob]         = make_float2(s02x + s13x, s02y + s13y);
    fb[ob + m]     = make_float2(c * t1x - s * t1y, c * t1y + s * t1x);
    fb[ob + 2 * m] = make_float2(c2 * t2x - s2 * t2y, c2 * t2y + s2 * t2x);
    fb[ob + 3 * m] = make_float2(c3 * t3x - s3 * t3y, c3 * t3y + s3 * t3x);
    v[0] = fb[lane];
    v[1] = fb[lane + 64];
    v[2] = fb[lane + 128];
    v[3] = fb[lane + 192];
  }
}

// ---------------------------------------------------------------------------
// Phase A: deformation -> bond, angle, projected (x,y) packed u16.8 scattered
// DIRECTLY into deterministic per-(pose, band, source-block) 64-slot chunks
// (rank from LDS atomic; no global reservation, no gcount, no second pass).
// Per-chunk counts written once at the end (single writer -> no zero-init).
// Straddle atoms (y0%32==31) duplicated into the next band's chunk.
// ---------------------------------------------------------------------------
__global__ __launch_bounds__(256) void k_deform(
    const float* __restrict__ c_nma, const float* __restrict__ delta_euler,
    const float* __restrict__ delta_shifts, const float* __restrict__ coords,
    const float* __restrict__ basis_x, const float* __restrict__ basis_y,
    const float* __restrict__ basis_z, const float* __restrict__ euler_base,
    const float* __restrict__ shifts_base,
    unsigned* __restrict__ xy_bkt, int* __restrict__ cnt,
    float* __restrict__ bond, float* __restrict__ angle) {
  __shared__ float cn_s[kBG][kL];
  __shared__ float rsh_s[kBG][8];
  __shared__ int bcnt[kBG][8];

  const int t = threadIdx.x;
  const int wave = t >> 6, lane = t & 63;
  const int bg = blockIdx.y * kBG;
  const int xb = blockIdx.x;
  const int n = xb * kTile + wave * kWOwn + lane;
  const bool owner = (lane < kWOwn) && (n < kN);
  const int nc = min(n, kN - 1);

  if (t < kBG * kL) cn_s[t / kL][t % kL] = c_nma[(bg + t / kL) * kL + (t % kL)];
  if (t < kBG) {
    int b = bg + t;
    float rot  = euler_base[b * 3 + 0] + delta_euler[b * 3 + 0];
    float tilt = euler_base[b * 3 + 1] + delta_euler[b * 3 + 1];
    float psi  = euler_base[b * 3 + 2] + delta_euler[b * 3 + 2];
    float ca = cosf(rot), sa = sinf(rot);
    float cb = cosf(tilt), sb = sinf(tilt);
    float cg = cosf(psi), sg = sinf(psi);
    rsh_s[t][0] = cg * cb * ca - sg * sa;
    rsh_s[t][1] = cg * cb * sa + sg * ca;
    rsh_s[t][2] = -cg * sb;
    rsh_s[t][3] = -sg * cb * ca - cg * sa;
    rsh_s[t][4] = -sg * cb * sa + cg * ca;
    rsh_s[t][5] = sg * sb;
    rsh_s[t][6] = shifts_base[b * 2 + 0] + delta_shifts[b * 2 + 0] + 128.0f;
    rsh_s[t][7] = shifts_base[b * 2 + 1] + delta_shifts[b * 2 + 1] + 128.0f;
  }
  if (t < kBG * 8) bcnt[t >> 3][t & 7] = 0;

  const float cx = coords[nc * 3 + 0];
  const float cy = coords[nc * 3 + 1];
  const float cz = coords[nc * 3 + 2];
  float bx[kL], by[kL], bz[kL];
  {
    const float4* px4 = reinterpret_cast<const float4*>(basis_x + (size_t)nc * kL);
    const float4* py4 = reinterpret_cast<const float4*>(basis_y + (size_t)nc * kL);
    const float4* pz4 = reinterpret_cast<const float4*>(basis_z + (size_t)nc * kL);
#pragma unroll
    for (int q = 0; q < 3; ++q) {
      float4 vx = px4[q], vy = py4[q], vz = pz4[q];
      bx[q * 4 + 0] = vx.x; bx[q * 4 + 1] = vx.y; bx[q * 4 + 2] = vx.z; bx[q * 4 + 3] = vx.w;
      by[q * 4 + 0] = vy.x; by[q * 4 + 1] = vy.y; by[q * 4 + 2] = vy.z; by[q * 4 + 3] = vy.w;
      bz[q * 4 + 0] = vz.x; bz[q * 4 + 1] = vz.y; bz[q * 4 + 2] = vz.z; bz[q * 4 + 3] = vz.w;
    }
  }
  __syncthreads();

#pragma unroll
  for (int bi = 0; bi < kBG; ++bi) {
    const int b = bg + bi;
    float px = cx, py = cy, pz = cz;
#pragma unroll
    for (int l = 0; l < kL; ++l) {
      float cc = cn_s[bi][l];
      px = fmaf(cc, bx[l], px);
      py = fmaf(cc, by[l], py);
      pz = fmaf(cc, bz[l], pz);
    }
    float p1x = __shfl_down(px, 1), p1y = __shfl_down(py, 1), p1z = __shfl_down(pz, 1);
    float dx = p1x - px, dy = p1y - py, dz = p1z - pz;
    float dd = fmaf(dx, dx, fmaf(dy, dy, dz * dz));
    float d1x = __shfl_down(dx, 1), d1y = __shfl_down(dy, 1), d1z = __shfl_down(dz, 1);

    if (owner) {
      float xr = fmaf(rsh_s[bi][0], px, fmaf(rsh_s[bi][1], py, fmaf(rsh_s[bi][2], pz, rsh_s[bi][6])));
      float yr = fmaf(rsh_s[bi][3], px, fmaf(rsh_s[bi][4], py, fmaf(rsh_s[bi][5], pz, rsh_s[bi][7])));
      xr = fminf(fmaxf(xr, 0.0f), 254.999f);
      yr = fminf(fmaxf(yr, 0.0f), 254.999f);
      unsigned xf = (unsigned)(xr * 256.0f);   // <= 65279 -> x0 <= 254
      unsigned yf = (unsigned)(yr * 256.0f);
      unsigned u = (yf << 16) | xf;
      unsigned y0i = yf >> 8;                  // 0..254
      unsigned band = y0i >> 5;                // 0..7
      int rank = atomicAdd(&bcnt[bi][band], 1);
      if (rank < kSlot)
        xy_bkt[(((size_t)b * 8 + band) * kNB + xb) * kSlot + rank] = u;
      if ((y0i & 31u) == 31u) {                // footprint straddles band edge
        unsigned band1 = band + 1;             // y0i<=223 -> band1<=7
        int r2 = atomicAdd(&bcnt[bi][band1], 1);
        if (r2 < kSlot)
          xy_bkt[(((size_t)b * 8 + band1) * kNB + xb) * kSlot + r2] = u;
      }
      if (n < kN - 1) {
        __builtin_nontemporal_store(sqrtf(dd + 1e-12f),
                                    &bond[(size_t)b * (kN - 1) + n]);
      }
      if (n < kN - 2) {
        float vv = fmaf(d1x, d1x, fmaf(d1y, d1y, d1z * d1z));
        float uv = -fmaf(dx, d1x, fmaf(dy, d1y, dz * d1z));
        float cosang = uv * rsqrtf(dd * vv);
        cosang = fminf(fmaxf(cosang, -0.9999f), 0.9999f);
        float ax = fabsf(cosang);
        float rt = sqrtf(1.0f - ax);
        float pp = fmaf(fmaf(fmaf(-0.0187293f, ax, 0.0742610f), ax, -0.2121144f),
                        ax, 1.5707288f);
        float res = rt * pp;
        __builtin_nontemporal_store((cosang >= 0.f) ? res : (float)M_PI - res,
                                    &angle[(size_t)b * (kN - 2) + n]);
      }
    }
  }
  __syncthreads();
  if (t < kBG * 8) {
    int po = t >> 3, bandx = t & 7;
    cnt[((bg + po) * 8 + bandx) * kNB + xb] = min(bcnt[po][bandx], kSlot);
  }
}

// ---------------------------------------------------------------------------
// Phase B (FUSED): splat from per-(pose,band) chunked slot lists into a
// 32x256 u18.14 LDS tile + 16 per-wave packed real row-FFTs, writing the
// Hermitian-reduced transposed spectrum FcT[b][kx][y] directly.
// grid: 32 poses * 8 bands, 1024 threads.
// ---------------------------------------------------------------------------
__global__ __launch_bounds__(1024) void k_splat_fft(
    const unsigned* __restrict__ xy_bkt, const int* __restrict__ cnt,
    float2* __restrict__ FcT) {
  __shared__ unsigned tile[32 * 256];
  __shared__ float2 fbuf[16][256];
  __shared__ float2 tw[128];
  __shared__ int cnt_s[kNB];
  const int t = threadIdx.x;
  const int b = blockIdx.x >> 3;
  const int band = blockIdx.x & 7;
  const int r0 = band * 32;
  build_tw(tw, t);
  for (int i = t; i < 32 * 256; i += 1024) tile[i] = 0u;
  for (int i = t; i < kNB; i += 1024) cnt_s[i] = cnt[(b * 8 + band) * kNB + i];
  __syncthreads();

  const int w = t >> 6, lane = t & 63;
  const unsigned* segbase = xy_bkt + ((size_t)b * 8 + band) * kNB * kSlot;

  auto splat1 = [&](unsigned u) {
    int yf = (int)(u >> 16);
    int xf = (int)(u & 0xFFFFu);
    int ry = (yf >> 8) - r0;                 // -1..31 (straddle dups at -1)
    int x0 = xf >> 8;
    int fx = xf & 255, fy = yf & 255;
    int gx = 256 - fx, gy = 256 - fy;
    if ((unsigned)ry < 32u) {
      int base = ry * 256 + x0;
      atomicAdd(&tile[base],     (unsigned)((gx * gy + 2) >> 2));
      atomicAdd(&tile[base + 1], (unsigned)((fx * gy + 2) >> 2));
    }
    if ((unsigned)(ry + 1) < 32u) {
      int base = (ry + 1) * 256 + x0;
      atomicAdd(&tile[base],     (unsigned)((gx * fy + 2) >> 2));
      atomicAdd(&tile[base + 1], (unsigned)((fx * fy + 2) >> 2));
    }
  };

  for (int j = w; j < kNB; j += 16) {        // wave processes whole chunks
    int cc = cnt_s[j];
    unsigned u = segbase[(size_t)j * kSlot + lane];
    if (lane < cc) splat1(u);
  }
  __syncthreads();

  // one wave per row-pair: rows 2w, 2w+1 packed as re+i*im
  const int rowA = 2 * w;
  constexpr float scale = 1.0f / 16384.0f;
  float2 v[4];
#pragma unroll
  for (int j = 0; j < 4; ++j) {
    int i = lane + 64 * j;
    v[j] = make_float2((float)tile[rowA * 256 + i] * scale,
                       (float)tile[(rowA + 1) * 256 + i] * scale);
  }
  fft256w<-1>(v, fbuf[w], lane, tw);
  float2* a = fbuf[w];                        // holds all 256 spectrum values
  const int y = r0 + rowA;
#pragma unroll
  for (int j = 0; j < 2; ++j) {
    int k = lane + 64 * j;
    float2 Zk = a[k], Zm = a[(256 - k) & 255];
    float4 o = make_float4(0.5f * (Zk.x + Zm.x), 0.5f * (Zk.y - Zm.y),
                           0.5f * (Zk.y + Zm.y), 0.5f * (Zm.x - Zk.x));
    *reinterpret_cast<float4*>(&FcT[((size_t)b * kKx + k) * kS + y]) = o;
  }
  if (lane == 0) {                            // Nyquist k=128
    float2 Zk = a[128];
    *reinterpret_cast<float4*>(&FcT[((size_t)b * kKx + 128) * kS + y]) =
        make_float4(Zk.x, 0.f, Zk.y, 0.f);
  }
}

// ---------------------------------------------------------------------------
// Column FFT * H * inverse column FFT; one wave per (pose, kx) column.
// grid: 32 poses * 33 blocks (4 cols/block); kx > 128 waves exit early.
// ---------------------------------------------------------------------------
__global__ __launch_bounds__(256) void k_fft_cols(float2* __restrict__ FcT,
                                                  const float* __restrict__ defocus) {
  __shared__ float2 fbuf[4][256];
  __shared__ float2 tw[128];
  const int t = threadIdx.x, w = t >> 6, lane = t & 63;
  build_tw(tw, t);
  const int b = blockIdx.x / 33;
  const int kx = (blockIdx.x % 33) * 4 + w;
  __syncthreads();                            // tw ready
  if (kx > 128) return;
  float2* col = FcT + ((size_t)b * kKx + kx) * kS;
  float2 v[4];
#pragma unroll
  for (int j = 0; j < 4; ++j) v[j] = col[lane + 64 * j];
  fft256w<-1>(v, fbuf[w], lane, tw);

  const float D = defocus[b];
  const float fxv = (float)kx * (1.0f / 256.0f);
  const float fx2 = fxv * fxv;
#pragma unroll
  for (int j = 0; j < 4; ++j) {
    int ky = lane + 64 * j;
    float fyv = (float)(ky < 128 ? ky : ky - 256) * (1.0f / 256.0f);
    float s2 = fyv * fyv + fx2;
    float G = __expf(-kGauss * s2);
    float chi = kA1 * D * s2 - kA2 * s2 * s2;
    float sn, cn;
    sincosf(chi, &sn, &cn);
    float H = G * (-(kW1 * sn + kQ0 * cn));
    v[j].x *= H;
    v[j].y *= H;
  }
  fft256w<1>(v, fbuf[w], lane, tw);
#pragma unroll
  for (int j = 0; j < 4; ++j) col[lane + 64 * j] = v[j];
}

// ---------------------------------------------------------------------------
// Inverse row FFT: one wave per row-pair (y=2p, 2p+1). Hermitian-extend the
// 129 stored kx into the full 256-pt spectrum per wave, then barrier-free
// inverse FFT; real parts -> two output rows. grid: 32 poses * 32 blocks.
// ---------------------------------------------------------------------------
__global__ __launch_bounds__(256) void k_fft_rows_inv(const float2* __restrict__ FcT,
                                                      float* __restrict__ out) {
  __shared__ float2 fbuf[4][256];
  __shared__ float4 smT[4][132];
  __shared__ float2 tw[128];
  const int t = threadIdx.x, w = t >> 6, lane = t & 63;
  build_tw(tw, t);
  const int b = blockIdx.x >> 5;
  const int pp = (blockIdx.x & 31) * 4 + w;   // pair 0..127
  const int y = 2 * pp;

  const float4* Fp = reinterpret_cast<const float4*>(FcT + (size_t)b * kKx * kS + y);
  const size_t kstep = kS / 2;                // float4s between consecutive k
  smT[w][lane]      = Fp[(size_t)lane * kstep];
  smT[w][lane + 64] = Fp[(size_t)(lane + 64) * kstep];
  if (lane == 0) smT[w][128] = Fp[(size_t)128 * kstep];
  __syncthreads();                            // tw ready (smT is per-wave)

  float2 v[4];
  {
    float4 f = smT[w][lane];
    v[0] = make_float2(f.x - f.w, f.y + f.z);
  }
  {
    float4 f = smT[w][lane + 64];
    v[1] = make_float2(f.x - f.w, f.y + f.z);
  }
  if (lane == 0) {
    float4 f = smT[w][128];
    v[2] = make_float2(f.x - f.w, f.y + f.z);
  } else {
    float4 f = smT[w][128 - lane];            // Hermitian: k=128+lane
    v[2] = make_float2(f.x + f.w, -f.y + f.z);
  }
  {
    float4 f = smT[w][64 - lane];             // Hermitian: k=192+lane
    v[3] = make_float2(f.x + f.w, -f.y + f.z);
  }
  fft256w<1>(v, fbuf[w], lane, tw);

  float* o0 = out + ((size_t)b * kS + y) * kS;
  float* o1 = o0 + kS;
#pragma unroll
  for (int j = 0; j < 4; ++j) {
    int i = lane + 64 * j;
    o0[i] = v[j].x * (1.0f / 65536.0f);
    o1[i] = v[j].y * (1.0f / 65536.0f);
  }
}

// ---------------------------------------------------------------------------
extern "C" void kernel_launch(void* const* d_in, const int* in_sizes, int n_in,
                              void* d_out, int out_size, void* d_ws, size_t ws_size,
                              hipStream_t stream) {
  const float* c_nma        = (const float*)d_in[0];
  const float* delta_euler  = (const float*)d_in[1];
  const float* delta_shifts = (const float*)d_in[2];
  const float* coords       = (const float*)d_in[3];
  const float* basis_x      = (const float*)d_in[4];
  const float* basis_y      = (const float*)d_in[5];
  const float* basis_z      = (const float*)d_in[6];
  const float* euler_base   = (const float*)d_in[7];
  const float* shifts_base  = (const float*)d_in[8];
  const float* defocus      = (const float*)d_in[9];

  float* out = (float*)d_out;
  float* decoded = out;                                   // B*S*S
  float* bond    = out + (size_t)kB * kS * kS;            // B*(N-1)
  float* angle   = bond + (size_t)kB * (kN - 1);          // B*(N-2)

  char* ws = (char*)d_ws;
  // xy_bkt: 32 poses * 8 bands * 404 blocks * 64 slots * 4B = 26.5 MB
  const size_t bktBytes = (size_t)kB * 8 * kNB * kSlot * sizeof(unsigned);
  unsigned* xy_bkt = (unsigned*)ws;
  int*      cnt    = (int*)(ws + bktBytes);                      // 413 KB
  float2*   FcT    = (float2*)(ws + (size_t)28 * 1024 * 1024);   // [28MB, 36.5MB)

  dim3 gd(kNB, kB / kBG);
  k_deform<<<gd, 256, 0, stream>>>(c_nma, delta_euler, delta_shifts, coords,
                                   basis_x, basis_y, basis_z, euler_base,
                                   shifts_base, xy_bkt, cnt, bond, angle);
  k_splat_fft<<<kB * 8, 1024, 0, stream>>>(xy_bkt, cnt, FcT);
  k_fft_cols<<<kB * 33, 256, 0, stream>>>(FcT, defocus);
  k_fft_rows_inv<<<kB * 32, 256, 0, stream>>>(FcT, decoded);
}